// Round 5
// baseline (920.732 us; speedup 1.0000x reference)
//
#include <hip/hip_runtime.h>
#include <hip/hip_bf16.h>

// Problem constants (fixed by reference)
#define N_NODES 50000
#define N_EDGES 500000
#define N_GRAPHS 512

// ---------------------------------------------------------------------------
// Packed fixed-point: u16 fixed point (scale 2^11) — legacy path only.
// ---------------------------------------------------------------------------
#define FXS16 2048.0f
#define FXI16 4.8828125e-4f  // 2^-11

__device__ __forceinline__ unsigned long long pk16x4(float4 v) {
    const unsigned long long a = (unsigned int)fmaf(v.x, FXS16, 0.5f);
    const unsigned long long b = (unsigned int)fmaf(v.y, FXS16, 0.5f);
    const unsigned long long c = (unsigned int)fmaf(v.z, FXS16, 0.5f);
    const unsigned long long d = (unsigned int)fmaf(v.w, FXS16, 0.5f);
    return a | (b << 16) | (c << 32) | (d << 48);
}

// MFMA fragment types
typedef __attribute__((ext_vector_type(8))) short bf16x8;
typedef __attribute__((ext_vector_type(4))) float f32x4;

// ---------------------------------------------------------------------------
// Prep: transpose weights to bf16 n-major: dst[n*K+k] = bf16(src[k*N+n]).
// ---------------------------------------------------------------------------
__global__ __launch_bounds__(256) void prep_kernel(
    const float* __restrict__ We2,  const float* __restrict__ Wn1,
    const float* __restrict__ Win1, const float* __restrict__ Wout1,
    const float* __restrict__ Wn2,  const float* __restrict__ Win2,
    const float* __restrict__ Wout2, const float* __restrict__ We1,
    __hip_bfloat16* __restrict__ Wt2,  __hip_bfloat16* __restrict__ Wn1t,
    __hip_bfloat16* __restrict__ Win1t,__hip_bfloat16* __restrict__ Wout1t,
    __hip_bfloat16* __restrict__ Wn2t, __hip_bfloat16* __restrict__ Win2t,
    __hip_bfloat16* __restrict__ Wout2t, __hip_bfloat16* __restrict__ We1t)
{
    const int b = blockIdx.x, t = threadIdx.x;
    const float* src; __hip_bfloat16* dst; int K, N, base;
    if (b < 128)      { src = We2;   dst = Wt2;    K = 256; N = 128; base = 0; }
    else if (b < 192) { src = Wn1;   dst = Wn1t;   K = 64;  N = 256; base = 128; }
    else if (b < 448) { src = Win1;  dst = Win1t;  K = 256; N = 256; base = 192; }
    else if (b < 704) { src = Wout1; dst = Wout1t; K = 256; N = 256; base = 448; }
    else if (b < 832) { src = Wn2;   dst = Wn2t;   K = 256; N = 128; base = 704; }
    else if (b < 896) { src = Win2;  dst = Win2t;  K = 128; N = 128; base = 832; }
    else if (b < 960) { src = Wout2; dst = Wout2t; K = 128; N = 128; base = 896; }
    else              { src = We1;   dst = We1t;   K = 32;  N = 256; base = 960; }
    const int i = (b - base) * 256 + t;
    const int n = i / K, k = i - n * K;
    dst[i] = __float2bfloat16(src[(size_t)k * N + n]);
}

// Convert raw edge features e [E,32] fp32 -> bf16 (gather source)
__global__ __launch_bounds__(256) void convert_e_kernel(
    const float* __restrict__ e, __hip_bfloat16* __restrict__ ebf)
{
    const long i = (long)blockIdx.x * 256 + threadIdx.x;   // 8 values each
    if (i * 8 >= (long)N_EDGES * 32) return;
    const float4 v0 = *(const float4*)&e[i * 8];
    const float4 v1 = *(const float4*)&e[i * 8 + 4];
    __hip_bfloat16* d = &ebf[i * 8];
    *(__hip_bfloat162*)&d[0] = __float22bfloat162_rn(make_float2(v0.x, v0.y));
    *(__hip_bfloat162*)&d[2] = __float22bfloat162_rn(make_float2(v0.z, v0.w));
    *(__hip_bfloat162*)&d[4] = __float22bfloat162_rn(make_float2(v1.x, v1.y));
    *(__hip_bfloat162*)&d[6] = __float22bfloat162_rn(make_float2(v1.z, v1.w));
}

// ===========================================================================
// =====================   CSR BUILD (count/scan/fill)   =====================
// ===========================================================================

#define NTILES 196   // ceil(50000/256)

__global__ __launch_bounds__(256) void count_kernel(
    const int* __restrict__ senders, const int* __restrict__ receivers,
    unsigned int* __restrict__ rc, unsigned int* __restrict__ sc)
{
    const int i = blockIdx.x * 256 + threadIdx.x;
    if (i < N_EDGES) {
        atomicAdd(&rc[receivers[i]], 1u);
        atomicAdd(&sc[senders[i]], 1u);
    }
}

__global__ __launch_bounds__(256) void scan_tile_sum(
    const unsigned int* __restrict__ rc, const unsigned int* __restrict__ sc,
    unsigned int* __restrict__ tsR, unsigned int* __restrict__ tsS)
{
    const int b = blockIdx.x;
    const int sel = (b >= NTILES);
    const int tile = sel ? b - NTILES : b;
    const unsigned int* src = sel ? sc : rc;
    unsigned int* ts = sel ? tsS : tsR;
    const int t = threadIdx.x;
    const int i = tile * 256 + t;
    unsigned int v = (i < N_NODES) ? src[i] : 0u;
    __shared__ unsigned int s[256];
    s[t] = v; __syncthreads();
    for (int off = 128; off > 0; off >>= 1) {
        if (t < off) s[t] += s[t + off];
        __syncthreads();
    }
    if (t == 0) ts[tile] = s[0];
}

__global__ __launch_bounds__(256) void scan_tile_offsets(
    unsigned int* __restrict__ tsR, unsigned int* __restrict__ tsS,
    int* __restrict__ roff, int* __restrict__ soff)
{
    __shared__ unsigned int s[256];
    const int t = threadIdx.x;
    for (int sel = 0; sel < 2; sel++) {
        unsigned int* ts = sel ? tsS : tsR;
        int* off = sel ? soff : roff;
        unsigned int v = (t < NTILES) ? ts[t] : 0u;
        s[t] = v; __syncthreads();
        for (int o = 1; o < 256; o <<= 1) {
            unsigned int x = (t >= o) ? s[t - o] : 0u;
            __syncthreads();
            s[t] += x;
            __syncthreads();
        }
        const unsigned int incl = s[t];
        if (t < NTILES) ts[t] = incl - v;
        if (t == NTILES - 1) off[N_NODES] = (int)incl;
        __syncthreads();
    }
}

__global__ __launch_bounds__(256) void scan_finalize(
    const unsigned int* __restrict__ rc, const unsigned int* __restrict__ sc,
    const unsigned int* __restrict__ tsR, const unsigned int* __restrict__ tsS,
    int* __restrict__ roff, int* __restrict__ soff,
    unsigned int* __restrict__ wpR, unsigned int* __restrict__ wpS)
{
    const int b = blockIdx.x;
    const int sel = (b >= NTILES);
    const int tile = sel ? b - NTILES : b;
    const unsigned int* src = sel ? sc : rc;
    const unsigned int* ts = sel ? tsS : tsR;
    int* off = sel ? soff : roff;
    unsigned int* wp = sel ? wpS : wpR;
    const int t = threadIdx.x, i = tile * 256 + t;
    unsigned int v = (i < N_NODES) ? src[i] : 0u;
    __shared__ unsigned int s[256];
    s[t] = v; __syncthreads();
    for (int o = 1; o < 256; o <<= 1) {
        unsigned int x = (t >= o) ? s[t - o] : 0u;
        __syncthreads();
        s[t] += x;
        __syncthreads();
    }
    const unsigned int excl = s[t] - v + ts[tile];
    if (i < N_NODES) { off[i] = (int)excl; wp[i] = excl; }
}

__global__ __launch_bounds__(256) void csr_fill(
    const int* __restrict__ senders, const int* __restrict__ receivers,
    unsigned int* __restrict__ wpR, unsigned int* __restrict__ wpS,
    int* __restrict__ csrR, int* __restrict__ csrS)
{
    const int i = blockIdx.x * 256 + threadIdx.x;
    if (i < N_EDGES) {
        csrR[atomicAdd(&wpR[receivers[i]], 1u)] = i;
        csrS[atomicAdd(&wpS[senders[i]], 1u)] = i;
    }
}

#define EPB 32
#define EBP 40    // bf16 e stride (32+8)
#define E1P 264
#define E2P 132

// ---------------------------------------------------------------------------
// Edge kernel: e1 via MFMA; e2 via MFMA; per-graph ge1/ge2/gecnt sums ONLY.
// ---------------------------------------------------------------------------
__global__ __launch_bounds__(256) void edge_kernel_e2(
    const float* __restrict__ e,
    const int* __restrict__ edge_graph,
    const __hip_bfloat16* __restrict__ We1t, const float* __restrict__ be1,
    const __hip_bfloat16* __restrict__ Wt2,
    const float* __restrict__ be2,
    float* __restrict__ ge1, float* __restrict__ ge2, float* __restrict__ gecnt)
{
    __shared__ __hip_bfloat16 eB[EPB * EBP];      // 2.5 KB
    __shared__ __hip_bfloat16 e1B[EPB * E1P];     // 16.5 KB
    __shared__ float e2L[EPB * E2P];              // 16.5 KB
    __shared__ int gidx[EPB];

    const int t = threadIdx.x;
    const long e0 = (long)blockIdx.x * EPB;

    // stage e -> bf16 LDS
    {
        const int j = t >> 3, c4 = (t & 7) * 4;
        const float4 v = *(const float4*)&e[(e0 + j) * 32 + c4];
        __hip_bfloat16* d = &eB[j * EBP + c4];
        *(__hip_bfloat162*)&d[0] = __float22bfloat162_rn(make_float2(v.x, v.y));
        *(__hip_bfloat162*)&d[2] = __float22bfloat162_rn(make_float2(v.z, v.w));
    }
    if (t < EPB) gidx[t] = edge_graph[e0 + t];
    __syncthreads();

    const int wv = t >> 6, ln = t & 63;
    const int r0 = ln & 15, q = ln >> 4;

    // e1 = relu(e @ We1 + be1) via MFMA: M=32 (2 mt), N=256, K=32
    #pragma unroll
    for (int mt = 0; mt < 2; mt++) {
        const bf16x8 a = *(const bf16x8*)&eB[(mt * 16 + r0) * EBP + q * 8];
        #pragma unroll
        for (int nn = 0; nn < 4; nn++) {
            const int n = (wv * 4 + nn) * 16 + r0;
            const bf16x8 wb = *(const bf16x8*)&We1t[(size_t)n * 32 + q * 8];
            f32x4 c = {0.f, 0.f, 0.f, 0.f};
            c = __builtin_amdgcn_mfma_f32_16x16x32_bf16(a, wb, c, 0, 0, 0);
            const float bz = be1[n];
            #pragma unroll
            for (int r = 0; r < 4; r++)
                e1B[(mt * 16 + q * 4 + r) * E1P + n] =
                    __float2bfloat16(fmaxf(c[r] + bz, 0.f));
        }
    }
    __syncthreads();

    // e2 = relu(e1 @ We2 + be2) via MFMA -> fp32 LDS
    {
        f32x4 acc[2][2] = {{{0.f,0.f,0.f,0.f},{0.f,0.f,0.f,0.f}},
                           {{0.f,0.f,0.f,0.f},{0.f,0.f,0.f,0.f}}};
        const int n0 = (2 * wv) * 16 + r0;
        const int n1 = (2 * wv + 1) * 16 + r0;
        #pragma unroll
        for (int kb = 0; kb < 8; kb++) {
            const int k0 = kb * 32 + q * 8;
            const bf16x8 a0 = *(const bf16x8*)&e1B[(r0) * E1P + k0];
            const bf16x8 a1 = *(const bf16x8*)&e1B[(16 + r0) * E1P + k0];
            const bf16x8 b0 = *(const bf16x8*)&Wt2[(size_t)n0 * 256 + k0];
            const bf16x8 b1 = *(const bf16x8*)&Wt2[(size_t)n1 * 256 + k0];
            acc[0][0] = __builtin_amdgcn_mfma_f32_16x16x32_bf16(a0, b0, acc[0][0], 0, 0, 0);
            acc[0][1] = __builtin_amdgcn_mfma_f32_16x16x32_bf16(a0, b1, acc[0][1], 0, 0, 0);
            acc[1][0] = __builtin_amdgcn_mfma_f32_16x16x32_bf16(a1, b0, acc[1][0], 0, 0, 0);
            acc[1][1] = __builtin_amdgcn_mfma_f32_16x16x32_bf16(a1, b1, acc[1][1], 0, 0, 0);
        }
        const float bz0 = be2[2 * wv * 16 + r0];
        const float bz1 = be2[(2 * wv + 1) * 16 + r0];
        #pragma unroll
        for (int mt = 0; mt < 2; mt++) {
            const int m = mt * 16 + q * 4;
            #pragma unroll
            for (int r = 0; r < 4; r++) {
                e2L[(m + r) * E2P + 2 * wv * 16 + r0]       = fmaxf(acc[mt][0][r] + bz0, 0.f);
                e2L[(m + r) * E2P + (2 * wv + 1) * 16 + r0] = fmaxf(acc[mt][1][r] + bz1, 0.f);
            }
        }
    }
    __syncthreads();

    // Per-graph edge sums (edge_graph sorted -> few runs per block)
    if (gidx[0] == gidx[EPB - 1]) {
        const int g = gidx[0];
        float s = 0.f;
        #pragma unroll
        for (int j = 0; j < EPB; j++) s += __bfloat162float(e1B[j * E1P + t]);
        atomicAdd(&ge1[(size_t)g * 256 + t], s);
        if (t < 128) {
            float s2 = 0.f;
            #pragma unroll
            for (int j = 0; j < EPB; j++) s2 += e2L[j * E2P + t];
            atomicAdd(&ge2[(size_t)g * 128 + t], s2);
        }
        if (t == 0) atomicAdd(&gecnt[g], (float)EPB);
    } else {
        int j = 0;
        while (j < EPB) {
            const int g = gidx[j];
            int j2 = j;
            float s = 0.f;
            while (j2 < EPB && gidx[j2] == g) { s += __bfloat162float(e1B[j2 * E1P + t]); j2++; }
            atomicAdd(&ge1[(size_t)g * 256 + t], s);
            if (t < 128) {
                float s2 = 0.f;
                for (int jj = j; jj < j2; jj++) s2 += e2L[jj * E2P + t];
                atomicAdd(&ge2[(size_t)g * 128 + t], s2);
            }
            if (t == 0) atomicAdd(&gecnt[g], (float)(j2 - j));
            j = j2;
        }
    }
}

// ---------------------------------------------------------------------------
// Aggregate kernel (v3): CHK=32 (LDS ~35 KB -> 4 blocks/CU), jog swizzle so
// every strided LDS access is bank-conflict-free, single indicator fragment
// per chunk shared by S1 and S2. Segment sums via indicator-MFMA in registers.
// Jog: row j placed at j*P + ((j>>3)&3)*32B. For S-reads (rows q*8+i) the jog
// key equals q, and 8*rowstride+32B = 8 banks (mod 32) for P=312/184, so the
// four q-groups occupy disjoint 8-bank sets. All b128 reads stay 16B-aligned.
// ---------------------------------------------------------------------------
#define ANPB 16
#define CHK 32
#define ESP 40     // eS stride (32+8) bf16
#define E1CP 312   // 256 ch + jog(<=48) + 8 pad
#define E2CP 184   // 128 ch + jog(<=48) + 8 pad
#define JADDR(j, c, P) ((j) * (P) + (c) + ((((j) >> 3) & 3) << 4))

__global__ __launch_bounds__(256) void agg_kernel(
    const __hip_bfloat16* __restrict__ ebf,
    const int* __restrict__ roff, const int* __restrict__ soff,
    const int* __restrict__ csrR, const int* __restrict__ csrS,
    const __hip_bfloat16* __restrict__ We1t, const float* __restrict__ be1,
    const __hip_bfloat16* __restrict__ Wt2, const float* __restrict__ be2,
    __hip_bfloat16* __restrict__ i1d, __hip_bfloat16* __restrict__ o1d,
    __hip_bfloat16* __restrict__ i2d, __hip_bfloat16* __restrict__ o2d)
{
    __shared__ __hip_bfloat16 eS[CHK * ESP];        // 2.5 KB
    __shared__ __hip_bfloat16 e1C[CHK * E1CP];      // 19.5 KB
    __shared__ __hip_bfloat16 e2C[CHK * E2CP];      // 11.5 KB
    __shared__ int idL[CHK];
    __shared__ int segL[CHK];
    __shared__ int offL[ANPB + 1];

    const int t = threadIdx.x;
    int b = blockIdx.x;
    const int side = (b >= (N_NODES / ANPB));
    if (side) b -= N_NODES / ANPB;
    const int n0 = b * ANPB;
    const int* off = side ? soff : roff;
    const int* lst = side ? csrS : csrR;
    __hip_bfloat16* d1 = side ? o1d : i1d;
    __hip_bfloat16* d2 = side ? o2d : i2d;

    if (t <= ANPB) offL[t] = off[n0 + t];
    __syncthreads();
    const int base = offL[0], end = offL[ANPB];

    const int wv = t >> 6, ln = t & 63;
    const int r0 = ln & 15, q = ln >> 4;

    // register accumulators: S1 = Ind.e1 (16x256), S2 = Ind.e2 (16x128)
    f32x4 s1[4] = {{0.f,0.f,0.f,0.f},{0.f,0.f,0.f,0.f},
                   {0.f,0.f,0.f,0.f},{0.f,0.f,0.f,0.f}};
    f32x4 s2[2] = {{0.f,0.f,0.f,0.f},{0.f,0.f,0.f,0.f}};

    float bz1[4], bz2[2];
    #pragma unroll
    for (int nn = 0; nn < 4; nn++) bz1[nn] = be1[(wv * 4 + nn) * 16 + r0];
    #pragma unroll
    for (int nn = 0; nn < 2; nn++) bz2[nn] = be2[(wv * 2 + nn) * 16 + r0];

    for (int cb = base; cb < end; cb += CHK) {
        const int cnt = min(CHK, end - cb);
        // stage ids + segment indices (t>=cnt -> seg -1 => indicator 0)
        if (t < CHK) {
            int sg = -1;
            if (t < cnt) {
                const int p = cb + t;
                idL[t] = lst[p];
                sg = 0;
                #pragma unroll
                for (int j = 1; j < ANPB; j++) sg += (p >= offL[j]) ? 1 : 0;
            }
            segL[t] = sg;
        }
        __syncthreads();
        // stage raw e rows (zero-pad tail): 4 lanes x 16B per row
        if (t < 128) {
            const int sl = t >> 2, cg = (t & 3) * 8;
            bf16x8 v = {0, 0, 0, 0, 0, 0, 0, 0};
            if (sl < cnt) v = *(const bf16x8*)&ebf[(size_t)idL[sl] * 32 + cg];
            *(bf16x8*)&eS[sl * ESP + cg] = v;
        }
        __syncthreads();

        // indicator fragment (once per chunk; reused by S1 and S2)
        bf16x8 ind;
        #pragma unroll
        for (int i = 0; i < 8; i++)
            ind[i] = (segL[q * 8 + i] == r0) ? (short)0x3F80 : (short)0;

        // e1 = relu(e @ We1 + be1): M=32 (2 mt), N=256, K=32
        #pragma unroll
        for (int mt = 0; mt < 2; mt++) {
            const bf16x8 a = *(const bf16x8*)&eS[(mt * 16 + r0) * ESP + q * 8];
            #pragma unroll
            for (int nn = 0; nn < 4; nn++) {
                const int n = (wv * 4 + nn) * 16 + r0;
                const bf16x8 wb = *(const bf16x8*)&We1t[(size_t)n * 32 + q * 8];
                f32x4 c = {0.f, 0.f, 0.f, 0.f};
                c = __builtin_amdgcn_mfma_f32_16x16x32_bf16(a, wb, c, 0, 0, 0);
                #pragma unroll
                for (int r = 0; r < 4; r++)
                    e1C[JADDR(mt * 16 + q * 4 + r, n, E1CP)] =
                        __float2bfloat16(fmaxf(c[r] + bz1[nn], 0.f));
            }
        }
        __syncthreads();

        // S1 += Ind @ e1   (K=32, single kstep; jog makes reads conflict-free)
        #pragma unroll
        for (int nn = 0; nn < 4; nn++) {
            const int n = (wv * 4 + nn) * 16 + r0;
            bf16x8 bfr;
            #pragma unroll
            for (int i = 0; i < 8; i++)
                bfr[i] = *(const short*)&e1C[JADDR(q * 8 + i, n, E1CP)];
            s1[nn] = __builtin_amdgcn_mfma_f32_16x16x32_bf16(ind, bfr, s1[nn], 0, 0, 0);
        }

        // e2 = relu(e1 @ We2 + be2): M=32, N=128, K=256 (8 ksteps)
        #pragma unroll
        for (int mt = 0; mt < 2; mt++) {
            f32x4 c[2] = {{0.f,0.f,0.f,0.f},{0.f,0.f,0.f,0.f}};
            #pragma unroll
            for (int ks = 0; ks < 8; ks++) {
                const bf16x8 a = *(const bf16x8*)&e1C[JADDR(mt * 16 + r0, ks * 32 + q * 8, E1CP)];
                #pragma unroll
                for (int nn = 0; nn < 2; nn++) {
                    const int n = (wv * 2 + nn) * 16 + r0;
                    const bf16x8 wb = *(const bf16x8*)&Wt2[(size_t)n * 256 + ks * 32 + q * 8];
                    c[nn] = __builtin_amdgcn_mfma_f32_16x16x32_bf16(a, wb, c[nn], 0, 0, 0);
                }
            }
            #pragma unroll
            for (int nn = 0; nn < 2; nn++) {
                const int n = (wv * 2 + nn) * 16 + r0;
                #pragma unroll
                for (int r = 0; r < 4; r++)
                    e2C[JADDR(mt * 16 + q * 4 + r, n, E2CP)] =
                        __float2bfloat16(fmaxf(c[nn][r] + bz2[nn], 0.f));
            }
        }
        __syncthreads();

        // S2 += Ind @ e2
        #pragma unroll
        for (int nn = 0; nn < 2; nn++) {
            const int n = (wv * 2 + nn) * 16 + r0;
            bf16x8 bfr;
            #pragma unroll
            for (int i = 0; i < 8; i++)
                bfr[i] = *(const short*)&e2C[JADDR(q * 8 + i, n, E2CP)];
            s2[nn] = __builtin_amdgcn_mfma_f32_16x16x32_bf16(ind, bfr, s2[nn], 0, 0, 0);
        }
        __syncthreads();   // protect segL/eS/e1C/e2C before next chunk
    }

    // means: dump register sums (scaled) to LDS (plain layout), then
    // coalesced global store. Lane (r0,q) holds rows m=q*4+r, col n.
    {
        float inv[4];
        #pragma unroll
        for (int r = 0; r < 4; r++) {
            const int m = q * 4 + r;
            const int deg = offL[m + 1] - offL[m];
            inv[r] = 1.f / (float)(deg > 0 ? deg : 1);
        }
        #pragma unroll
        for (int nn = 0; nn < 4; nn++) {
            const int n = (wv * 4 + nn) * 16 + r0;
            #pragma unroll
            for (int r = 0; r < 4; r++)
                e1C[(q * 4 + r) * E1CP + n] = __float2bfloat16(s1[nn][r] * inv[r]);
        }
        #pragma unroll
        for (int nn = 0; nn < 2; nn++) {
            const int n = (wv * 2 + nn) * 16 + r0;
            #pragma unroll
            for (int r = 0; r < 4; r++)
                e2C[(q * 4 + r) * E2CP + n] = __float2bfloat16(s2[nn][r] * inv[r]);
        }
    }
    __syncthreads();
    for (int i = t; i < ANPB * 32; i += 256) {
        const int j = i >> 5, c8 = (i & 31) * 8;
        *(bf16x8*)&d1[(size_t)(n0 + j) * 256 + c8] = *(const bf16x8*)&e1C[j * E1CP + c8];
    }
    for (int i = t; i < ANPB * 16; i += 256) {
        const int j = i >> 4, c8 = (i & 15) * 8;
        *(bf16x8*)&d2[(size_t)(n0 + j) * 128 + c8] = *(const bf16x8*)&e2C[j * E2CP + c8];
    }
}

// ---------------------------------------------------------------------------
// Node kernel (dense): load dense bf16 mean matrices -> LDS; MFMA n1, n2;
// per-graph fp32 atomic sums.
// ---------------------------------------------------------------------------
#define NPB 16
#define XP  72
#define K1P 264
#define K2P 136

__global__ __launch_bounds__(256) void node_kernel_dense(
    const float* __restrict__ x,
    const int* __restrict__ node_graph,
    const __hip_bfloat16* __restrict__ i1d, const __hip_bfloat16* __restrict__ o1d,
    const __hip_bfloat16* __restrict__ i2d, const __hip_bfloat16* __restrict__ o2d,
    const __hip_bfloat16* __restrict__ Wn1t, const __hip_bfloat16* __restrict__ Win1t,
    const __hip_bfloat16* __restrict__ Wout1t, const float* __restrict__ bn1,
    const __hip_bfloat16* __restrict__ Wn2t, const __hip_bfloat16* __restrict__ Win2t,
    const __hip_bfloat16* __restrict__ Wout2t, const float* __restrict__ bn2,
    float* __restrict__ gn1, float* __restrict__ gn2, float* __restrict__ gncnt)
{
    __shared__ __hip_bfloat16 xB[NPB * XP];
    __shared__ __hip_bfloat16 i1B[NPB * K1P];
    __shared__ __hip_bfloat16 o1B[NPB * K1P];
    __shared__ __hip_bfloat16 i2B[NPB * K2P];
    __shared__ __hip_bfloat16 o2B[NPB * K2P];
    __shared__ __hip_bfloat16 n1B[NPB * K1P];
    __shared__ __hip_bfloat16 n2B[NPB * K2P];
    __shared__ int gI[NPB];

    const int t = threadIdx.x;
    const long n0 = (long)blockIdx.x * NPB;

    if (t < NPB) gI[t] = node_graph[n0 + t];
    for (int i = t; i < NPB * 16; i += 256) {
        const int j = i >> 4, c4 = (i & 15) * 4;
        const float4 v = *(const float4*)&x[(n0 + j) * 64 + c4];
        *(__hip_bfloat162*)&xB[j * XP + c4]     = __float22bfloat162_rn(make_float2(v.x, v.y));
        *(__hip_bfloat162*)&xB[j * XP + c4 + 2] = __float22bfloat162_rn(make_float2(v.z, v.w));
    }
    for (int i = t; i < NPB * 32; i += 256) {
        const int j = i >> 5, c8 = (i & 31) * 8;
        *(bf16x8*)&i1B[j * K1P + c8] = *(const bf16x8*)&i1d[(size_t)(n0 + j) * 256 + c8];
        *(bf16x8*)&o1B[j * K1P + c8] = *(const bf16x8*)&o1d[(size_t)(n0 + j) * 256 + c8];
    }
    for (int i = t; i < NPB * 16; i += 256) {
        const int j = i >> 4, c8 = (i & 15) * 8;
        *(bf16x8*)&i2B[j * K2P + c8] = *(const bf16x8*)&i2d[(size_t)(n0 + j) * 128 + c8];
        *(bf16x8*)&o2B[j * K2P + c8] = *(const bf16x8*)&o2d[(size_t)(n0 + j) * 128 + c8];
    }
    __syncthreads();

    const int wv = t >> 6, ln = t & 63;
    const int r0 = ln & 15, q = ln >> 4;

    // ---- n1 MFMA
    {
        f32x4 acc[4] = {{0.f,0.f,0.f,0.f},{0.f,0.f,0.f,0.f},
                        {0.f,0.f,0.f,0.f},{0.f,0.f,0.f,0.f}};
        #pragma unroll
        for (int ks = 0; ks < 2; ks++) {
            const int k0 = ks * 32 + q * 8;
            const bf16x8 a = *(const bf16x8*)&xB[r0 * XP + k0];
            #pragma unroll
            for (int nn = 0; nn < 4; nn++) {
                const int n = (wv * 4 + nn) * 16 + r0;
                const bf16x8 b = *(const bf16x8*)&Wn1t[(size_t)n * 64 + k0];
                acc[nn] = __builtin_amdgcn_mfma_f32_16x16x32_bf16(a, b, acc[nn], 0, 0, 0);
            }
        }
        #pragma unroll
        for (int ks = 0; ks < 8; ks++) {
            const int k0 = ks * 32 + q * 8;
            const bf16x8 a = *(const bf16x8*)&i1B[r0 * K1P + k0];
            #pragma unroll
            for (int nn = 0; nn < 4; nn++) {
                const int n = (wv * 4 + nn) * 16 + r0;
                const bf16x8 b = *(const bf16x8*)&Win1t[(size_t)n * 256 + k0];
                acc[nn] = __builtin_amdgcn_mfma_f32_16x16x32_bf16(a, b, acc[nn], 0, 0, 0);
            }
        }
        #pragma unroll
        for (int ks = 0; ks < 8; ks++) {
            const int k0 = ks * 32 + q * 8;
            const bf16x8 a = *(const bf16x8*)&o1B[r0 * K1P + k0];
            #pragma unroll
            for (int nn = 0; nn < 4; nn++) {
                const int n = (wv * 4 + nn) * 16 + r0;
                const bf16x8 b = *(const bf16x8*)&Wout1t[(size_t)n * 256 + k0];
                acc[nn] = __builtin_amdgcn_mfma_f32_16x16x32_bf16(a, b, acc[nn], 0, 0, 0);
            }
        }
        #pragma unroll
        for (int nn = 0; nn < 4; nn++) {
            const int n = (wv * 4 + nn) * 16 + r0;
            const float bz = bn1[n];
            #pragma unroll
            for (int r = 0; r < 4; r++) {
                const int m = q * 4 + r;
                n1B[m * K1P + n] = __float2bfloat16(fmaxf(acc[nn][r] + bz, 0.f));
            }
        }
    }
    __syncthreads();

    // ---- per-graph n1 sums
    if (gI[0] == gI[NPB - 1]) {
        float s = 0.f;
        #pragma unroll
        for (int j = 0; j < NPB; j++) s += __bfloat162float(n1B[j * K1P + t]);
        atomicAdd(&gn1[(size_t)gI[0] * 256 + t], s);
        if (t == 0) atomicAdd(&gncnt[gI[0]], (float)NPB);
    } else {
        int j = 0;
        while (j < NPB) {
            const int g = gI[j];
            int j2 = j;
            float s = 0.f;
            while (j2 < NPB && gI[j2] == g) { s += __bfloat162float(n1B[j2 * K1P + t]); j2++; }
            atomicAdd(&gn1[(size_t)g * 256 + t], s);
            if (t == 0) atomicAdd(&gncnt[g], (float)(j2 - j));
            j = j2;
        }
    }

    // ---- n2 MFMA
    {
        f32x4 acc[2] = {{0.f,0.f,0.f,0.f},{0.f,0.f,0.f,0.f}};
        #pragma unroll
        for (int ks = 0; ks < 8; ks++) {
            const int k0 = ks * 32 + q * 8;
            const bf16x8 a = *(const bf16x8*)&n1B[r0 * K1P + k0];
            #pragma unroll
            for (int nn = 0; nn < 2; nn++) {
                const int n = (wv * 2 + nn) * 16 + r0;
                const bf16x8 b = *(const bf16x8*)&Wn2t[(size_t)n * 256 + k0];
                acc[nn] = __builtin_amdgcn_mfma_f32_16x16x32_bf16(a, b, acc[nn], 0, 0, 0);
            }
        }
        #pragma unroll
        for (int ks = 0; ks < 4; ks++) {
            const int k0 = ks * 32 + q * 8;
            const bf16x8 a = *(const bf16x8*)&i2B[r0 * K2P + k0];
            #pragma unroll
            for (int nn = 0; nn < 2; nn++) {
                const int n = (wv * 2 + nn) * 16 + r0;
                const bf16x8 b = *(const bf16x8*)&Win2t[(size_t)n * 128 + k0];
                acc[nn] = __builtin_amdgcn_mfma_f32_16x16x32_bf16(a, b, acc[nn], 0, 0, 0);
            }
        }
        #pragma unroll
        for (int ks = 0; ks < 4; ks++) {
            const int k0 = ks * 32 + q * 8;
            const bf16x8 a = *(const bf16x8*)&o2B[r0 * K2P + k0];
            #pragma unroll
            for (int nn = 0; nn < 2; nn++) {
                const int n = (wv * 2 + nn) * 16 + r0;
                const bf16x8 b = *(const bf16x8*)&Wout2t[(size_t)n * 128 + k0];
                acc[nn] = __builtin_amdgcn_mfma_f32_16x16x32_bf16(a, b, acc[nn], 0, 0, 0);
            }
        }
        #pragma unroll
        for (int nn = 0; nn < 2; nn++) {
            const int n = (wv * 2 + nn) * 16 + r0;
            const float bz = bn2[n];
            #pragma unroll
            for (int r = 0; r < 4; r++) {
                const int m = q * 4 + r;
                n2B[m * K2P + n] = __float2bfloat16(fmaxf(acc[nn][r] + bz, 0.f));
            }
        }
    }
    __syncthreads();

    // ---- per-graph n2 sums
    if (t < 128) {
        if (gI[0] == gI[NPB - 1]) {
            float s = 0.f;
            #pragma unroll
            for (int j = 0; j < NPB; j++) s += __bfloat162float(n2B[j * K2P + t]);
            atomicAdd(&gn2[(size_t)gI[0] * 128 + t], s);
        } else {
            int j = 0;
            while (j < NPB) {
                const int g = gI[j];
                int j2 = j;
                float s = 0.f;
                while (j2 < NPB && gI[j2] == g) { s += __bfloat162float(n2B[j2 * K2P + t]); j2++; }
                atomicAdd(&gn2[(size_t)g * 128 + t], s);
                j = j2;
            }
        }
    }
}

// ---------------------------------------------------------------------------
// Graph kernel: one block per graph. u1, u2, state_value, action MLP, output.
// ---------------------------------------------------------------------------
__global__ __launch_bounds__(256) void graph_kernel(
    const float* __restrict__ u,
    const float* __restrict__ a,
    const float* __restrict__ ge1, const float* __restrict__ ge2,
    const float* __restrict__ gecnt,
    const float* __restrict__ gn1, const float* __restrict__ gn2,
    const float* __restrict__ gncnt,
    const float* __restrict__ Wg1, const float* __restrict__ Wgn1,
    const float* __restrict__ Wge1, const float* __restrict__ bg1,
    const float* __restrict__ Wg2, const float* __restrict__ Wgn2,
    const float* __restrict__ Wge2, const float* __restrict__ bg2,
    const float* __restrict__ Wga, const float* __restrict__ bga,
    const float* __restrict__ Wa1, const float* __restrict__ ba1,
    const float* __restrict__ Wa2, const float* __restrict__ ba2,
    const float* __restrict__ Wa3, const float* __restrict__ ba3,
    float* __restrict__ out)
{
    const int g = blockIdx.x;
    const int t = threadIdx.x;
    __shared__ float uL[64], mn1[256], me1[256], mn2[128], me2[128];
    __shared__ float u1L[256], u2L[128], hL[144], h1L[256], h2L[256];
    __shared__ float red[4];

    const float ec = 1.f / fmaxf(gecnt[g], 1.f);
    const float nc = 1.f / fmaxf(gncnt[g], 1.f);
    if (t < 64) uL[t] = u[(size_t)g * 64 + t];
    mn1[t] = gn1[(size_t)g * 256 + t] * nc;
    me1[t] = ge1[(size_t)g * 256 + t] * ec;
    if (t < 128) {
        mn2[t] = gn2[(size_t)g * 128 + t] * nc;
        me2[t] = ge2[(size_t)g * 128 + t] * ec;
    }
    if (t >= 136 && t < 144) hL[t] = 0.f;
    __syncthreads();

    {
        float acc = bg1[t];
        for (int k = 0; k < 64; k++)  acc = fmaf(uL[k],  Wg1[(size_t)k * 256 + t], acc);
        for (int k = 0; k < 256; k++) acc = fmaf(mn1[k], Wgn1[(size_t)k * 256 + t], acc);
        for (int k = 0; k < 256; k++) acc = fmaf(me1[k], Wge1[(size_t)k * 256 + t], acc);
        u1L[t] = fmaxf(acc, 0.f);
    }
    __syncthreads();
    if (t < 128) {
        float acc = bg2[t];
        for (int k = 0; k < 256; k++) acc = fmaf(u1L[k], Wg2[(size_t)k * 128 + t], acc);
        for (int k = 0; k < 128; k++) acc = fmaf(mn2[k], Wgn2[(size_t)k * 128 + t], acc);
        for (int k = 0; k < 128; k++) acc = fmaf(me2[k], Wge2[(size_t)k * 128 + t], acc);
        u2L[t] = fmaxf(acc, 0.f);
    }
    __syncthreads();
    if (t < 128) {
        float acc = bga[t];
        for (int k = 0; k < 128; k++) acc = fmaf(u2L[k], Wga[(size_t)k * 128 + t], acc);
        hL[t] = acc;
    }
    if (t >= 128 && t < 136) hL[t] = a[(size_t)g * 8 + (t - 128)];
    __syncthreads();
    {
        float acc = ba1[t];
        for (int k = 0; k < 136; k++) acc = fmaf(hL[k], Wa1[(size_t)k * 256 + t], acc);
        h1L[t] = fmaxf(acc, 0.f);
    }
    __syncthreads();
    {
        float acc = ba2[t];
        for (int k = 0; k < 256; k++) acc = fmaf(h1L[k], Wa2[(size_t)k * 256 + t], acc);
        h2L[t] = fmaxf(acc, 0.f);
    }
    __syncthreads();
    {
        float p = h2L[t] * Wa3[t];
        for (int off = 32; off > 0; off >>= 1) p += __shfl_down(p, off, 64);
        if ((t & 63) == 0) red[t >> 6] = p;
        __syncthreads();
        if (t == 0) out[g] = red[0] + red[1] + red[2] + red[3] + ba3[0];
    }
}

// ===========================================================================
// ==================   LEGACY ATOMIC-SCATTER PATH (fallback)  ===============
// ===========================================================================

__global__ __launch_bounds__(256) void edge_kernel(
    const float* __restrict__ e,
    const int* __restrict__ senders,
    const int* __restrict__ receivers,
    const int* __restrict__ edge_graph,
    const float* __restrict__ We1, const float* __restrict__ be1,
    const __hip_bfloat16* __restrict__ Wt2,
    const float* __restrict__ be2,
    unsigned long long* __restrict__ inc1u, unsigned long long* __restrict__ out1u,
    unsigned long long* __restrict__ inc2u, unsigned long long* __restrict__ out2u,
    float* __restrict__ rcnt, float* __restrict__ scnt,
    float* __restrict__ ge1, float* __restrict__ ge2, float* __restrict__ gecnt)
{
    __shared__ float eL[EPB * 32];
    __shared__ __hip_bfloat16 e1B[EPB * E1P];
    __shared__ float e2L[EPB * E2P];
    __shared__ int ridx[EPB], sidx[EPB], gidx[EPB];

    const int t = threadIdx.x;
    const long e0 = (long)blockIdx.x * EPB;

    for (int i = t; i < EPB * 32; i += 256) eL[i] = e[e0 * 32 + i];
    if (t < EPB) {
        ridx[t] = receivers[e0 + t];
        sidx[t] = senders[e0 + t];
        gidx[t] = edge_graph[e0 + t];
    }
    __syncthreads();

    {
        const int c0 = (t & 63) * 4;
        const int jb = (t >> 6) * 8;
        float4 acc[8];
        const float4 b4 = *(const float4*)&be1[c0];
        #pragma unroll
        for (int j = 0; j < 8; j++) acc[j] = b4;
        for (int k = 0; k < 32; k += 4) {
            float4 v[8];
            #pragma unroll
            for (int j = 0; j < 8; j++) v[j] = *(const float4*)&eL[(jb + j) * 32 + k];
            #pragma unroll
            for (int kk = 0; kk < 4; kk++) {
                const float4 w = *(const float4*)&We1[(size_t)(k + kk) * 256 + c0];
                #pragma unroll
                for (int j = 0; j < 8; j++) {
                    const float vv = ((const float*)&v[j])[kk];
                    acc[j].x = fmaf(vv, w.x, acc[j].x);
                    acc[j].y = fmaf(vv, w.y, acc[j].y);
                    acc[j].z = fmaf(vv, w.z, acc[j].z);
                    acc[j].w = fmaf(vv, w.w, acc[j].w);
                }
            }
        }
        #pragma unroll
        for (int j = 0; j < 8; j++) {
            const float2 p0 = make_float2(fmaxf(acc[j].x, 0.f), fmaxf(acc[j].y, 0.f));
            const float2 p1 = make_float2(fmaxf(acc[j].z, 0.f), fmaxf(acc[j].w, 0.f));
            *(__hip_bfloat162*)&e1B[(jb + j) * E1P + c0]     = __float22bfloat162_rn(p0);
            *(__hip_bfloat162*)&e1B[(jb + j) * E1P + c0 + 2] = __float22bfloat162_rn(p1);
        }
    }
    __syncthreads();

    {
        const int wv = t >> 6, ln = t & 63;
        const int r0 = ln & 15, q = ln >> 4;
        f32x4 acc[2][2] = {{{0.f,0.f,0.f,0.f},{0.f,0.f,0.f,0.f}},
                           {{0.f,0.f,0.f,0.f},{0.f,0.f,0.f,0.f}}};
        const int n0 = (2 * wv) * 16 + r0;
        const int n1 = (2 * wv + 1) * 16 + r0;
        #pragma unroll
        for (int kb = 0; kb < 8; kb++) {
            const int k0 = kb * 32 + q * 8;
            const bf16x8 a0 = *(const bf16x8*)&e1B[(r0) * E1P + k0];
            const bf16x8 a1 = *(const bf16x8*)&e1B[(16 + r0) * E1P + k0];
            const bf16x8 b0 = *(const bf16x8*)&Wt2[(size_t)n0 * 256 + k0];
            const bf16x8 b1 = *(const bf16x8*)&Wt2[(size_t)n1 * 256 + k0];
            acc[0][0] = __builtin_amdgcn_mfma_f32_16x16x32_bf16(a0, b0, acc[0][0], 0, 0, 0);
            acc[0][1] = __builtin_amdgcn_mfma_f32_16x16x32_bf16(a0, b1, acc[0][1], 0, 0, 0);
            acc[1][0] = __builtin_amdgcn_mfma_f32_16x16x32_bf16(a1, b0, acc[1][0], 0, 0, 0);
            acc[1][1] = __builtin_amdgcn_mfma_f32_16x16x32_bf16(a1, b1, acc[1][1], 0, 0, 0);
        }
        const float bz0 = be2[2 * wv * 16 + r0];
        const float bz1 = be2[(2 * wv + 1) * 16 + r0];
        #pragma unroll
        for (int mt = 0; mt < 2; mt++) {
            const int m = mt * 16 + q * 4;
            #pragma unroll
            for (int r = 0; r < 4; r++) {
                e2L[(m + r) * E2P + 2 * wv * 16 + r0]       = fmaxf(acc[mt][0][r] + bz0, 0.f);
                e2L[(m + r) * E2P + (2 * wv + 1) * 16 + r0] = fmaxf(acc[mt][1][r] + bz1, 0.f);
            }
        }
    }
    __syncthreads();

    {
        const int w = t & 63;
        const int ep = (t >> 6) & 1;
        unsigned long long* arr = (t < 128) ? inc1u : out1u;
        const int* idx = (t < 128) ? ridx : sidx;
        #pragma unroll
        for (int jj = 0; jj < EPB / 2; jj++) {
            const int j = jj * 2 + ep;
            const float2 v0 = __bfloat1622float2(*(const __hip_bfloat162*)&e1B[j * E1P + 4 * w]);
            const float2 v1 = __bfloat1622float2(*(const __hip_bfloat162*)&e1B[j * E1P + 4 * w + 2]);
            float4 v; v.x = v0.x; v.y = v0.y; v.z = v1.x; v.w = v1.y;
            atomicAdd(&arr[(size_t)idx[j] * 64 + w], pk16x4(v));
        }
    }
    {
        const int w = t & 31;
        const int eq = (t >> 5) & 3;
        unsigned long long* arr = (t < 128) ? inc2u : out2u;
        const int* idx = (t < 128) ? ridx : sidx;
        #pragma unroll
        for (int jj = 0; jj < EPB / 4; jj++) {
            const int j = jj * 4 + eq;
            const float4 v = *(const float4*)&e2L[j * E2P + 4 * w];
            atomicAdd(&arr[(size_t)idx[j] * 32 + w], pk16x4(v));
        }
    }
    if (gidx[0] == gidx[EPB - 1]) {
        const int g = gidx[0];
        float s = 0.f;
        #pragma unroll
        for (int j = 0; j < EPB; j++) s += __bfloat162float(e1B[j * E1P + t]);
        atomicAdd(&ge1[(size_t)g * 256 + t], s);
        if (t < 128) {
            float s2 = 0.f;
            #pragma unroll
            for (int j = 0; j < EPB; j++) s2 += e2L[j * E2P + t];
            atomicAdd(&ge2[(size_t)g * 128 + t], s2);
        }
        if (t == 0) atomicAdd(&gecnt[g], (float)EPB);
    } else {
        int j = 0;
        while (j < EPB) {
            const int g = gidx[j];
            int j2 = j;
            float s = 0.f;
            while (j2 < EPB && gidx[j2] == g) { s += __bfloat162float(e1B[j2 * E1P + t]); j2++; }
            atomicAdd(&ge1[(size_t)g * 256 + t], s);
            if (t < 128) {
                float s2 = 0.f;
                for (int jj = j; jj < j2; jj++) s2 += e2L[jj * E2P + t];
                atomicAdd(&ge2[(size_t)g * 128 + t], s2);
            }
            if (t == 0) atomicAdd(&gecnt[g], (float)(j2 - j));
            j = j2;
        }
    }
    if (t < EPB) {
        atomicAdd(&rcnt[ridx[t]], 1.f);
        atomicAdd(&scnt[sidx[t]], 1.f);
    }
}

__global__ __launch_bounds__(256) void node_kernel(
    const float* __restrict__ x,
    const int* __restrict__ node_graph,
    const unsigned long long* __restrict__ inc1u, const unsigned long long* __restrict__ out1u,
    const unsigned long long* __restrict__ inc2u, const unsigned long long* __restrict__ out2u,
    const float* __restrict__ rcnt, const float* __restrict__ scnt,
    const __hip_bfloat16* __restrict__ Wn1t, const __hip_bfloat16* __restrict__ Win1t,
    const __hip_bfloat16* __restrict__ Wout1t, const float* __restrict__ bn1,
    const __hip_bfloat16* __restrict__ Wn2t, const __hip_bfloat16* __restrict__ Win2t,
    const __hip_bfloat16* __restrict__ Wout2t, const float* __restrict__ bn2,
    float* __restrict__ gn1, float* __restrict__ gn2, float* __restrict__ gncnt)
{
    __shared__ __hip_bfloat16 xB[NPB * XP];
    __shared__ __hip_bfloat16 i1B[NPB * K1P];
    __shared__ __hip_bfloat16 o1B[NPB * K1P];
    __shared__ __hip_bfloat16 i2B[NPB * K2P];
    __shared__ __hip_bfloat16 o2B[NPB * K2P];
    __shared__ __hip_bfloat16 n1B[NPB * K1P];
    __shared__ __hip_bfloat16 n2B[NPB * K2P];
    __shared__ int gI[NPB];
    __shared__ float rrcp[NPB], srcp[NPB];

    const int t = threadIdx.x;
    const long n0 = (long)blockIdx.x * NPB;

    if (t < NPB) {
        gI[t] = node_graph[n0 + t];
        rrcp[t] = FXI16 / fmaxf(rcnt[n0 + t], 1.f);
        srcp[t] = FXI16 / fmaxf(scnt[n0 + t], 1.f);
    }
    for (int i = t; i < NPB * 16; i += 256) {
        const int j = i >> 4, c4 = (i & 15) * 4;
        const float4 v = *(const float4*)&x[(n0 + j) * 64 + c4];
        *(__hip_bfloat162*)&xB[j * XP + c4]     = __float22bfloat162_rn(make_float2(v.x, v.y));
        *(__hip_bfloat162*)&xB[j * XP + c4 + 2] = __float22bfloat162_rn(make_float2(v.z, v.w));
    }
    __syncthreads();

    for (int i = t; i < NPB * 64; i += 256) {
        const int j = i >> 6, w = i & 63;
        const size_t n = (size_t)(n0 + j);
        const unsigned long long av = inc1u[n * 64 + w];
        const unsigned long long bv = out1u[n * 64 + w];
        const float rr = rrcp[j], sr = srcp[j];
        const float2 a01 = make_float2((float)(unsigned int)(av & 0xFFFF) * rr,
                                       (float)(unsigned int)((av >> 16) & 0xFFFF) * rr);
        const float2 a23 = make_float2((float)(unsigned int)((av >> 32) & 0xFFFF) * rr,
                                       (float)(unsigned int)(av >> 48) * rr);
        const float2 b01 = make_float2((float)(unsigned int)(bv & 0xFFFF) * sr,
                                       (float)(unsigned int)((bv >> 16) & 0xFFFF) * sr);
        const float2 b23 = make_float2((float)(unsigned int)((bv >> 32) & 0xFFFF) * sr,
                                       (float)(unsigned int)(bv >> 48) * sr);
        *(__hip_bfloat162*)&i1B[j * K1P + 4 * w]     = __float22bfloat162_rn(a01);
        *(__hip_bfloat162*)&i1B[j * K1P + 4 * w + 2] = __float22bfloat162_rn(a23);
        *(__hip_bfloat162*)&o1B[j * K1P + 4 * w]     = __float22bfloat162_rn(b01);
        *(__hip_bfloat162*)&o1B[j * K1P + 4 * w + 2] = __float22bfloat162_rn(b23);
    }
    for (int i = t; i < NPB * 32; i += 256) {
        const int j = i >> 5, w = i & 31;
        const size_t n = (size_t)(n0 + j);
        const unsigned long long av = inc2u[n * 32 + w];
        const unsigned long long bv = out2u[n * 32 + w];
        const float rr = rrcp[j], sr = srcp[j];
        const float2 a01 = make_float2((float)(unsigned int)(av & 0xFFFF) * rr,
                                       (float)(unsigned int)((av >> 16) & 0xFFFF) * rr);
        const float2 a23 = make_float2((float)(unsigned int)((av >> 32) & 0xFFFF) * rr,
                                       (float)(unsigned int)(av >> 48) * rr);
        const float2 b01 = make_float2((float)(unsigned int)(bv & 0xFFFF) * sr,
                                       (float)(unsigned int)((bv >> 16) & 0xFFFF) * sr);
        const float2 b23 = make_float2((float)(unsigned int)((bv >> 32) & 0xFFFF) * sr,
                                       (float)(unsigned int)(bv >> 48) * sr);
        *(__hip_bfloat162*)&i2B[j * K2P + 4 * w]     = __float22bfloat162_rn(a01);
        *(__hip_bfloat162*)&i2B[j * K2P + 4 * w + 2] = __float22bfloat162_rn(a23);
        *(__hip_bfloat162*)&o2B[j * K2P + 4 * w]     = __float22bfloat162_rn(b01);
        *(__hip_bfloat162*)&o2B[j * K2P + 4 * w + 2] = __float22bfloat162_rn(b23);
    }
    __syncthreads();

    const int wv = t >> 6, ln = t & 63;
    const int r0 = ln & 15, q = ln >> 4;

    {
        f32x4 acc[4] = {{0.f,0.f,0.f,0.f},{0.f,0.f,0.f,0.f},
                        {0.f,0.f,0.f,0.f},{0.f,0.f,0.f,0.f}};
        #pragma unroll
        for (int ks = 0; ks < 2; ks++) {
            const int k0 = ks * 32 + q * 8;
            const bf16x8 a = *(const bf16x8*)&xB[r0 * XP + k0];
            #pragma unroll
            for (int nn = 0; nn < 4; nn++) {
                const int n = (wv * 4 + nn) * 16 + r0;
                const bf16x8 b = *(const bf16x8*)&Wn1t[(size_t)n * 64 + k0];
                acc[nn] = __builtin_amdgcn_mfma_f32_16x16x32_bf16(a, b, acc[nn], 0, 0, 0);
            }
        }
        #pragma unroll
        for (int ks = 0; ks < 8; ks++) {
            const int k0 = ks * 32 + q * 8;
            const bf16x8 a = *(const bf16x8*)&i1B[r0 * K1P + k0];
            #pragma unroll
            for (int nn = 0; nn < 4; nn++) {
                const int n = (wv * 4 + nn) * 16 + r0;
                const bf16x8 b = *(const bf16x8*)&Win1t[(size_t)n * 256 + k0];
                acc[nn] = __builtin_amdgcn_mfma_f32_16x16x32_bf16(a, b, acc[nn], 0, 0, 0);
            }
        }
        #pragma unroll
        for (int ks = 0; ks < 8; ks++) {
            const int k0 = ks * 32 + q * 8;
            const bf16x8 a = *(const bf16x8*)&o1B[r0 * K1P + k0];
            #pragma unroll
            for (int nn = 0; nn < 4; nn++) {
                const int n = (wv * 4 + nn) * 16 + r0;
                const bf16x8 b = *(const bf16x8*)&Wout1t[(size_t)n * 256 + k0];
                acc[nn] = __builtin_amdgcn_mfma_f32_16x16x32_bf16(a, b, acc[nn], 0, 0, 0);
            }
        }
        #pragma unroll
        for (int nn = 0; nn < 4; nn++) {
            const int n = (wv * 4 + nn) * 16 + r0;
            const float bz = bn1[n];
            #pragma unroll
            for (int r = 0; r < 4; r++) {
                const int m = q * 4 + r;
                n1B[m * K1P + n] = __float2bfloat16(fmaxf(acc[nn][r] + bz, 0.f));
            }
        }
    }
    __syncthreads();

    if (gI[0] == gI[NPB - 1]) {
        float s = 0.f;
        #pragma unroll
        for (int j = 0; j < NPB; j++) s += __bfloat162float(n1B[j * K1P + t]);
        atomicAdd(&gn1[(size_t)gI[0] * 256 + t], s);
        if (t == 0) atomicAdd(&gncnt[gI[0]], (float)NPB);
    } else {
        int j = 0;
        while (j < NPB) {
            const int g = gI[j];
            int j2 = j;
            float s = 0.f;
            while (j2 < NPB && gI[j2] == g) { s += __bfloat162float(n1B[j2 * K1P + t]); j2++; }
            atomicAdd(&gn1[(size_t)g * 256 + t], s);
            if (t == 0) atomicAdd(&gncnt[g], (float)(j2 - j));
            j = j2;
        }
    }

    {
        f32x4 acc[2] = {{0.f,0.f,0.f,0.f},{0.f,0.f,0.f,0.f}};
        #pragma unroll
        for (int ks = 0; ks < 8; ks++) {
            const int k0 = ks * 32 + q * 8;
            const bf16x8 a = *(const bf16x8*)&n1B[r0 * K1P + k0];
            #pragma unroll
            for (int nn = 0; nn < 2; nn++) {
                const int n = (wv * 2 + nn) * 16 + r0;
                const bf16x8 b = *(const bf16x8*)&Wn2t[(size_t)n * 256 + k0];
                acc[nn] = __builtin_amdgcn_mfma_f32_16x16x32_bf16(a, b, acc[nn], 0, 0, 0);
            }
        }
        #pragma unroll
        for (int ks = 0; ks < 4; ks++) {
            const int k0 = ks * 32 + q * 8;
            const bf16x8 a = *(const bf16x8*)&i2B[r0 * K2P + k0];
            #pragma unroll
            for (int nn = 0; nn < 2; nn++) {
                const int n = (wv * 2 + nn) * 16 + r0;
                const bf16x8 b = *(const bf16x8*)&Win2t[(size_t)n * 128 + k0];
                acc[nn] = __builtin_amdgcn_mfma_f32_16x16x32_bf16(a, b, acc[nn], 0, 0, 0);
            }
        }
        #pragma unroll
        for (int ks = 0; ks < 4; ks++) {
            const int k0 = ks * 32 + q * 8;
            const bf16x8 a = *(const bf16x8*)&o2B[r0 * K2P + k0];
            #pragma unroll
            for (int nn = 0; nn < 2; nn++) {
                const int n = (wv * 2 + nn) * 16 + r0;
                const bf16x8 b = *(const bf16x8*)&Wout2t[(size_t)n * 128 + k0];
                acc[nn] = __builtin_amdgcn_mfma_f32_16x16x32_bf16(a, b, acc[nn], 0, 0, 0);
            }
        }
        #pragma unroll
        for (int nn = 0; nn < 2; nn++) {
            const int n = (wv * 2 + nn) * 16 + r0;
            const float bz = bn2[n];
            #pragma unroll
            for (int r = 0; r < 4; r++) {
                const int m = q * 4 + r;
                n2B[m * K2P + n] = __float2bfloat16(fmaxf(acc[nn][r] + bz, 0.f));
            }
        }
    }
    __syncthreads();

    if (t < 128) {
        if (gI[0] == gI[NPB - 1]) {
            float s = 0.f;
            #pragma unroll
            for (int j = 0; j < NPB; j++) s += __bfloat162float(n2B[j * K2P + t]);
            atomicAdd(&gn2[(size_t)gI[0] * 128 + t], s);
        } else {
            int j = 0;
            while (j < NPB) {
                const int g = gI[j];
                int j2 = j;
                float s = 0.f;
                while (j2 < NPB && gI[j2] == g) { s += __bfloat162float(n2B[j2 * K2P + t]); j2++; }
                atomicAdd(&gn2[(size_t)g * 128 + t], s);
                j = j2;
            }
        }
    }
}

// ---------------------------------------------------------------------------
extern "C" void kernel_launch(void* const* d_in, const int* in_sizes, int n_in,
                              void* d_out, int out_size, void* d_ws, size_t ws_size,
                              hipStream_t stream) {
    const float* x          = (const float*)d_in[0];
    const float* e          = (const float*)d_in[1];
    const float* u          = (const float*)d_in[2];
    const float* a          = (const float*)d_in[3];
    const int*   senders    = (const int*)d_in[4];
    const int*   receivers  = (const int*)d_in[5];
    const int*   node_graph = (const int*)d_in[6];
    const int*   edge_graph = (const int*)d_in[7];
    const float* We1 = (const float*)d_in[8];  const float* be1 = (const float*)d_in[9];
    const float* Wn1 = (const float*)d_in[10]; const float* Win1 = (const float*)d_in[11];
    const float* Wout1 = (const float*)d_in[12]; const float* bn1 = (const float*)d_in[13];
    const float* Wg1 = (const float*)d_in[14]; const float* Wgn1 = (const float*)d_in[15];
    const float* Wge1 = (const float*)d_in[16]; const float* bg1 = (const float*)d_in[17];
    const float* We2 = (const float*)d_in[18]; const float* be2 = (const float*)d_in[19];
    const float* Wn2 = (const float*)d_in[20]; const float* Win2 = (const float*)d_in[21];
    const float* Wout2 = (const float*)d_in[22]; const float* bn2 = (const float*)d_in[23];
    const float* Wg2 = (const float*)d_in[24]; const float* Wgn2 = (const float*)d_in[25];
    const float* Wge2 = (const float*)d_in[26]; const float* bg2 = (const float*)d_in[27];
    const float* Wga = (const float*)d_in[28]; const float* bga = (const float*)d_in[29];
    const float* Wa1 = (const float*)d_in[30]; const float* ba1 = (const float*)d_in[31];
    const float* Wa2 = (const float*)d_in[32]; const float* ba2 = (const float*)d_in[33];
    const float* Wa3 = (const float*)d_in[34]; const float* ba3 = (const float*)d_in[35];

    // ---------------- recompute-aggregate CSR path (~116 MB) ----------------
    {
        char* p = (char*)d_ws;
        auto take = [&p](size_t bytes) {
            char* q = p; p += (bytes + 15) & ~(size_t)15; return q;
        };
        // zeroed region (single small memset)
        unsigned int* rcntU = (unsigned int*)take((size_t)N_NODES * 4);
        unsigned int* scntU = (unsigned int*)take((size_t)N_NODES * 4);
        float* ge1   = (float*)take((size_t)N_GRAPHS * 256 * 4);
        float* ge2   = (float*)take((size_t)N_GRAPHS * 128 * 4);
        float* gecnt = (float*)take((size_t)N_GRAPHS * 4);
        float* gn1   = (float*)take((size_t)N_GRAPHS * 256 * 4);
        float* gn2   = (float*)take((size_t)N_GRAPHS * 128 * 4);
        float* gncnt = (float*)take((size_t)N_GRAPHS * 4);
        const size_t zero_bytes = (size_t)(p - (char*)d_ws);
        // fully-overwritten region
        int* roff = (int*)take((size_t)(N_NODES + 1) * 4);
        int* soff = (int*)take((size_t)(N_NODES + 1) * 4);
        unsigned int* wpR = (unsigned int*)take((size_t)N_NODES * 4);
        unsigned int* wpS = (unsigned int*)take((size_t)N_NODES * 4);
        unsigned int* tsR = (unsigned int*)take(256 * 4);
        unsigned int* tsS = (unsigned int*)take(256 * 4);
        int* csrR = (int*)take((size_t)N_EDGES * 4);
        int* csrS = (int*)take((size_t)N_EDGES * 4);
        __hip_bfloat16* ebf = (__hip_bfloat16*)take((size_t)N_EDGES * 32 * 2);
        // dense bf16 mean matrices
        __hip_bfloat16* i1d = (__hip_bfloat16*)take((size_t)N_NODES * 256 * 2);
        __hip_bfloat16* o1d = (__hip_bfloat16*)take((size_t)N_NODES * 256 * 2);
        __hip_bfloat16* i2d = (__hip_bfloat16*)take((size_t)N_NODES * 128 * 2);
        __hip_bfloat16* o2d = (__hip_bfloat16*)take((size_t)N_NODES * 128 * 2);
        // bf16 transposed weights
        __hip_bfloat16* Wt2    = (__hip_bfloat16*)take((size_t)128 * 256 * 2);
        __hip_bfloat16* Wn1t   = (__hip_bfloat16*)take((size_t)256 * 64 * 2);
        __hip_bfloat16* Win1t  = (__hip_bfloat16*)take((size_t)256 * 256 * 2);
        __hip_bfloat16* Wout1t = (__hip_bfloat16*)take((size_t)256 * 256 * 2);
        __hip_bfloat16* Wn2t   = (__hip_bfloat16*)take((size_t)128 * 256 * 2);
        __hip_bfloat16* Win2t  = (__hip_bfloat16*)take((size_t)128 * 128 * 2);
        __hip_bfloat16* Wout2t = (__hip_bfloat16*)take((size_t)128 * 128 * 2);
        __hip_bfloat16* We1t   = (__hip_bfloat16*)take((size_t)256 * 32 * 2);
        const size_t needed = (size_t)(p - (char*)d_ws);

        if (ws_size >= needed) {
            hipMemsetAsync(d_ws, 0, zero_bytes, stream);

            prep_kernel<<<992, 256, 0, stream>>>(
                We2, Wn1, Win1, Wout1, Wn2, Win2, Wout2, We1,
                Wt2, Wn1t, Win1t, Wout1t, Wn2t, Win2t, Wout2t, We1t);

            convert_e_kernel<<<(N_EDGES * 32 / 8 + 255) / 256, 256, 0, stream>>>(e, ebf);

            count_kernel<<<(N_EDGES + 255) / 256, 256, 0, stream>>>(
                senders, receivers, rcntU, scntU);
            scan_tile_sum<<<2 * NTILES, 256, 0, stream>>>(rcntU, scntU, tsR, tsS);
            scan_tile_offsets<<<1, 256, 0, stream>>>(tsR, tsS, roff, soff);
            scan_finalize<<<2 * NTILES, 256, 0, stream>>>(
                rcntU, scntU, tsR, tsS, roff, soff, wpR, wpS);
            csr_fill<<<(N_EDGES + 255) / 256, 256, 0, stream>>>(
                senders, receivers, wpR, wpS, csrR, csrS);

            edge_kernel_e2<<<N_EDGES / EPB, 256, 0, stream>>>(
                e, edge_graph, We1t, be1, Wt2, be2, ge1, ge2, gecnt);

            agg_kernel<<<2 * (N_NODES / ANPB), 256, 0, stream>>>(
                ebf, roff, soff, csrR, csrS, We1t, be1, Wt2, be2,
                i1d, o1d, i2d, o2d);

            node_kernel_dense<<<N_NODES / NPB, 256, 0, stream>>>(
                x, node_graph, i1d, o1d, i2d, o2d,
                Wn1t, Win1t, Wout1t, bn1, Wn2t, Win2t, Wout2t, bn2,
                gn1, gn2, gncnt);

            graph_kernel<<<N_GRAPHS, 256, 0, stream>>>(
                u, a, ge1, ge2, gecnt, gn1, gn2, gncnt,
                Wg1, Wgn1, Wge1, bg1, Wg2, Wgn2, Wge2, bg2,
                Wga, bga, Wa1, ba1, Wa2, ba2, Wa3, ba3, (float*)d_out);
            return;
        }
    }

    // ---------------- legacy atomic-scatter path (fallback) ----------------
    unsigned long long* uw = (unsigned long long*)d_ws;
    unsigned long long* inc1u = uw;                       uw += (size_t)N_NODES * 64;
    unsigned long long* out1u = uw;                       uw += (size_t)N_NODES * 64;
    unsigned long long* inc2u = uw;                       uw += (size_t)N_NODES * 32;
    unsigned long long* out2u = uw;                       uw += (size_t)N_NODES * 32;
    float* fw = (float*)uw;
    float* rcnt = fw;  fw += N_NODES;
    float* scnt = fw;  fw += N_NODES;
    float* ge1  = fw;  fw += (size_t)N_GRAPHS * 256;
    float* ge2  = fw;  fw += (size_t)N_GRAPHS * 128;
    float* gecnt = fw; fw += N_GRAPHS;
    float* gn1  = fw;  fw += (size_t)N_GRAPHS * 256;
    float* gn2  = fw;  fw += (size_t)N_GRAPHS * 128;
    float* gncnt = fw; fw += N_GRAPHS;
    const size_t total_bytes = (char*)fw - (char*)d_ws;
    __hip_bfloat16* bw = (__hip_bfloat16*)fw;
    __hip_bfloat16* Wt2    = bw;  bw += 128 * 256;
    __hip_bfloat16* Wn1t   = bw;  bw += 256 * 64;
    __hip_bfloat16* Win1t  = bw;  bw += 256 * 256;
    __hip_bfloat16* Wout1t = bw;  bw += 256 * 256;
    __hip_bfloat16* Wn2t   = bw;  bw += 128 * 256;
    __hip_bfloat16* Win2t  = bw;  bw += 128 * 128;
    __hip_bfloat16* Wout2t = bw;  bw += 128 * 128;
    __hip_bfloat16* We1t   = bw;  bw += 256 * 32;

    hipMemsetAsync(d_ws, 0, total_bytes, stream);

    prep_kernel<<<992, 256, 0, stream>>>(
        We2, Wn1, Win1, Wout1, Wn2, Win2, Wout2, We1,
        Wt2, Wn1t, Win1t, Wout1t, Wn2t, Win2t, Wout2t, We1t);

    edge_kernel<<<N_EDGES / EPB, 256, 0, stream>>>(
        e, senders, receivers, edge_graph, We1, be1, Wt2, be2,
        inc1u, out1u, inc2u, out2u, rcnt, scnt, ge1, ge2, gecnt);

    node_kernel<<<N_NODES / NPB, 256, 0, stream>>>(
        x, node_graph, inc1u, out1u, inc2u, out2u, rcnt, scnt,
        Wn1t, Win1t, Wout1t, bn1, Wn2t, Win2t, Wout2t, bn2, gn1, gn2, gncnt);

    graph_kernel<<<N_GRAPHS, 256, 0, stream>>>(
        u, a, ge1, ge2, gecnt, gn1, gn2, gncnt,
        Wg1, Wgn1, Wge1, bg1, Wg2, Wgn2, Wge2, bg2,
        Wga, bga, Wa1, ba1, Wa2, ba2, Wa3, ba3, (float*)d_out);
}

// Round 6
// 898.270 us; speedup vs baseline: 1.0250x; 1.0250x over previous
//
#include <hip/hip_runtime.h>
#include <hip/hip_bf16.h>

// Problem constants (fixed by reference)
#define N_NODES 50000
#define N_EDGES 500000
#define N_GRAPHS 512

// ---------------------------------------------------------------------------
// Packed fixed-point: u16 fixed point (scale 2^11) — legacy path only.
// ---------------------------------------------------------------------------
#define FXS16 2048.0f
#define FXI16 4.8828125e-4f  // 2^-11

__device__ __forceinline__ unsigned long long pk16x4(float4 v) {
    const unsigned long long a = (unsigned int)fmaf(v.x, FXS16, 0.5f);
    const unsigned long long b = (unsigned int)fmaf(v.y, FXS16, 0.5f);
    const unsigned long long c = (unsigned int)fmaf(v.z, FXS16, 0.5f);
    const unsigned long long d = (unsigned int)fmaf(v.w, FXS16, 0.5f);
    return a | (b << 16) | (c << 32) | (d << 48);
}

// MFMA fragment types
typedef __attribute__((ext_vector_type(8))) short bf16x8;
typedef __attribute__((ext_vector_type(4))) float f32x4;

// ---------------------------------------------------------------------------
// Prep: transpose weights to bf16 n-major: dst[n*K+k] = bf16(src[k*N+n]).
// ---------------------------------------------------------------------------
__global__ __launch_bounds__(256) void prep_kernel(
    const float* __restrict__ We2,  const float* __restrict__ Wn1,
    const float* __restrict__ Win1, const float* __restrict__ Wout1,
    const float* __restrict__ Wn2,  const float* __restrict__ Win2,
    const float* __restrict__ Wout2, const float* __restrict__ We1,
    __hip_bfloat16* __restrict__ Wt2,  __hip_bfloat16* __restrict__ Wn1t,
    __hip_bfloat16* __restrict__ Win1t,__hip_bfloat16* __restrict__ Wout1t,
    __hip_bfloat16* __restrict__ Wn2t, __hip_bfloat16* __restrict__ Win2t,
    __hip_bfloat16* __restrict__ Wout2t, __hip_bfloat16* __restrict__ We1t)
{
    const int b = blockIdx.x, t = threadIdx.x;
    const float* src; __hip_bfloat16* dst; int K, N, base;
    if (b < 128)      { src = We2;   dst = Wt2;    K = 256; N = 128; base = 0; }
    else if (b < 192) { src = Wn1;   dst = Wn1t;   K = 64;  N = 256; base = 128; }
    else if (b < 448) { src = Win1;  dst = Win1t;  K = 256; N = 256; base = 192; }
    else if (b < 704) { src = Wout1; dst = Wout1t; K = 256; N = 256; base = 448; }
    else if (b < 832) { src = Wn2;   dst = Wn2t;   K = 256; N = 128; base = 704; }
    else if (b < 896) { src = Win2;  dst = Win2t;  K = 128; N = 128; base = 832; }
    else if (b < 960) { src = Wout2; dst = Wout2t; K = 128; N = 128; base = 896; }
    else              { src = We1;   dst = We1t;   K = 32;  N = 256; base = 960; }
    const int i = (b - base) * 256 + t;
    const int n = i / K, k = i - n * K;
    dst[i] = __float2bfloat16(src[(size_t)k * N + n]);
}

// Convert raw edge features e [E,32] fp32 -> bf16 (gather source)
__global__ __launch_bounds__(256) void convert_e_kernel(
    const float* __restrict__ e, __hip_bfloat16* __restrict__ ebf)
{
    const long i = (long)blockIdx.x * 256 + threadIdx.x;   // 8 values each
    if (i * 8 >= (long)N_EDGES * 32) return;
    const float4 v0 = *(const float4*)&e[i * 8];
    const float4 v1 = *(const float4*)&e[i * 8 + 4];
    __hip_bfloat16* d = &ebf[i * 8];
    *(__hip_bfloat162*)&d[0] = __float22bfloat162_rn(make_float2(v0.x, v0.y));
    *(__hip_bfloat162*)&d[2] = __float22bfloat162_rn(make_float2(v0.z, v0.w));
    *(__hip_bfloat162*)&d[4] = __float22bfloat162_rn(make_float2(v1.x, v1.y));
    *(__hip_bfloat162*)&d[6] = __float22bfloat162_rn(make_float2(v1.z, v1.w));
}

// ===========================================================================
// =====================   CSR BUILD (count/scan/fill)   =====================
// ===========================================================================

#define NTILES 196   // ceil(50000/256)

__global__ __launch_bounds__(256) void count_kernel(
    const int* __restrict__ senders, const int* __restrict__ receivers,
    unsigned int* __restrict__ rc, unsigned int* __restrict__ sc)
{
    const int i = blockIdx.x * 256 + threadIdx.x;
    if (i < N_EDGES) {
        atomicAdd(&rc[receivers[i]], 1u);
        atomicAdd(&sc[senders[i]], 1u);
    }
}

__global__ __launch_bounds__(256) void scan_tile_sum(
    const unsigned int* __restrict__ rc, const unsigned int* __restrict__ sc,
    unsigned int* __restrict__ tsR, unsigned int* __restrict__ tsS)
{
    const int b = blockIdx.x;
    const int sel = (b >= NTILES);
    const int tile = sel ? b - NTILES : b;
    const unsigned int* src = sel ? sc : rc;
    unsigned int* ts = sel ? tsS : tsR;
    const int t = threadIdx.x;
    const int i = tile * 256 + t;
    unsigned int v = (i < N_NODES) ? src[i] : 0u;
    __shared__ unsigned int s[256];
    s[t] = v; __syncthreads();
    for (int off = 128; off > 0; off >>= 1) {
        if (t < off) s[t] += s[t + off];
        __syncthreads();
    }
    if (t == 0) ts[tile] = s[0];
}

__global__ __launch_bounds__(256) void scan_tile_offsets(
    unsigned int* __restrict__ tsR, unsigned int* __restrict__ tsS,
    int* __restrict__ roff, int* __restrict__ soff)
{
    __shared__ unsigned int s[256];
    const int t = threadIdx.x;
    for (int sel = 0; sel < 2; sel++) {
        unsigned int* ts = sel ? tsS : tsR;
        int* off = sel ? soff : roff;
        unsigned int v = (t < NTILES) ? ts[t] : 0u;
        s[t] = v; __syncthreads();
        for (int o = 1; o < 256; o <<= 1) {
            unsigned int x = (t >= o) ? s[t - o] : 0u;
            __syncthreads();
            s[t] += x;
            __syncthreads();
        }
        const unsigned int incl = s[t];
        if (t < NTILES) ts[t] = incl - v;
        if (t == NTILES - 1) off[N_NODES] = (int)incl;
        __syncthreads();
    }
}

__global__ __launch_bounds__(256) void scan_finalize(
    const unsigned int* __restrict__ rc, const unsigned int* __restrict__ sc,
    const unsigned int* __restrict__ tsR, const unsigned int* __restrict__ tsS,
    int* __restrict__ roff, int* __restrict__ soff,
    unsigned int* __restrict__ wpR, unsigned int* __restrict__ wpS)
{
    const int b = blockIdx.x;
    const int sel = (b >= NTILES);
    const int tile = sel ? b - NTILES : b;
    const unsigned int* src = sel ? sc : rc;
    const unsigned int* ts = sel ? tsS : tsR;
    int* off = sel ? soff : roff;
    unsigned int* wp = sel ? wpS : wpR;
    const int t = threadIdx.x, i = tile * 256 + t;
    unsigned int v = (i < N_NODES) ? src[i] : 0u;
    __shared__ unsigned int s[256];
    s[t] = v; __syncthreads();
    for (int o = 1; o < 256; o <<= 1) {
        unsigned int x = (t >= o) ? s[t - o] : 0u;
        __syncthreads();
        s[t] += x;
        __syncthreads();
    }
    const unsigned int excl = s[t] - v + ts[tile];
    if (i < N_NODES) { off[i] = (int)excl; wp[i] = excl; }
}

__global__ __launch_bounds__(256) void csr_fill(
    const int* __restrict__ senders, const int* __restrict__ receivers,
    unsigned int* __restrict__ wpR, unsigned int* __restrict__ wpS,
    int* __restrict__ csrR, int* __restrict__ csrS)
{
    const int i = blockIdx.x * 256 + threadIdx.x;
    if (i < N_EDGES) {
        csrR[atomicAdd(&wpR[receivers[i]], 1u)] = i;
        csrS[atomicAdd(&wpS[senders[i]], 1u)] = i;
    }
}

#define EPB 32
#define EBP 40    // bf16 e stride (32+8)
#define E1P 264
#define E2P 132

// ---------------------------------------------------------------------------
// Edge kernel: e1 via MFMA; e2 via MFMA; per-graph ge1/ge2/gecnt sums ONLY.
// ---------------------------------------------------------------------------
__global__ __launch_bounds__(256) void edge_kernel_e2(
    const float* __restrict__ e,
    const int* __restrict__ edge_graph,
    const __hip_bfloat16* __restrict__ We1t, const float* __restrict__ be1,
    const __hip_bfloat16* __restrict__ Wt2,
    const float* __restrict__ be2,
    float* __restrict__ ge1, float* __restrict__ ge2, float* __restrict__ gecnt)
{
    __shared__ __hip_bfloat16 eB[EPB * EBP];      // 2.5 KB
    __shared__ __hip_bfloat16 e1B[EPB * E1P];     // 16.5 KB
    __shared__ float e2L[EPB * E2P];              // 16.5 KB
    __shared__ int gidx[EPB];

    const int t = threadIdx.x;
    const long e0 = (long)blockIdx.x * EPB;

    // stage e -> bf16 LDS
    {
        const int j = t >> 3, c4 = (t & 7) * 4;
        const float4 v = *(const float4*)&e[(e0 + j) * 32 + c4];
        __hip_bfloat16* d = &eB[j * EBP + c4];
        *(__hip_bfloat162*)&d[0] = __float22bfloat162_rn(make_float2(v.x, v.y));
        *(__hip_bfloat162*)&d[2] = __float22bfloat162_rn(make_float2(v.z, v.w));
    }
    if (t < EPB) gidx[t] = edge_graph[e0 + t];
    __syncthreads();

    const int wv = t >> 6, ln = t & 63;
    const int r0 = ln & 15, q = ln >> 4;

    // e1 = relu(e @ We1 + be1) via MFMA: M=32 (2 mt), N=256, K=32
    #pragma unroll
    for (int mt = 0; mt < 2; mt++) {
        const bf16x8 a = *(const bf16x8*)&eB[(mt * 16 + r0) * EBP + q * 8];
        #pragma unroll
        for (int nn = 0; nn < 4; nn++) {
            const int n = (wv * 4 + nn) * 16 + r0;
            const bf16x8 wb = *(const bf16x8*)&We1t[(size_t)n * 32 + q * 8];
            f32x4 c = {0.f, 0.f, 0.f, 0.f};
            c = __builtin_amdgcn_mfma_f32_16x16x32_bf16(a, wb, c, 0, 0, 0);
            const float bz = be1[n];
            #pragma unroll
            for (int r = 0; r < 4; r++)
                e1B[(mt * 16 + q * 4 + r) * E1P + n] =
                    __float2bfloat16(fmaxf(c[r] + bz, 0.f));
        }
    }
    __syncthreads();

    // e2 = relu(e1 @ We2 + be2) via MFMA -> fp32 LDS
    {
        f32x4 acc[2][2] = {{{0.f,0.f,0.f,0.f},{0.f,0.f,0.f,0.f}},
                           {{0.f,0.f,0.f,0.f},{0.f,0.f,0.f,0.f}}};
        const int n0 = (2 * wv) * 16 + r0;
        const int n1 = (2 * wv + 1) * 16 + r0;
        #pragma unroll
        for (int kb = 0; kb < 8; kb++) {
            const int k0 = kb * 32 + q * 8;
            const bf16x8 a0 = *(const bf16x8*)&e1B[(r0) * E1P + k0];
            const bf16x8 a1 = *(const bf16x8*)&e1B[(16 + r0) * E1P + k0];
            const bf16x8 b0 = *(const bf16x8*)&Wt2[(size_t)n0 * 256 + k0];
            const bf16x8 b1 = *(const bf16x8*)&Wt2[(size_t)n1 * 256 + k0];
            acc[0][0] = __builtin_amdgcn_mfma_f32_16x16x32_bf16(a0, b0, acc[0][0], 0, 0, 0);
            acc[0][1] = __builtin_amdgcn_mfma_f32_16x16x32_bf16(a0, b1, acc[0][1], 0, 0, 0);
            acc[1][0] = __builtin_amdgcn_mfma_f32_16x16x32_bf16(a1, b0, acc[1][0], 0, 0, 0);
            acc[1][1] = __builtin_amdgcn_mfma_f32_16x16x32_bf16(a1, b1, acc[1][1], 0, 0, 0);
        }
        const float bz0 = be2[2 * wv * 16 + r0];
        const float bz1 = be2[(2 * wv + 1) * 16 + r0];
        #pragma unroll
        for (int mt = 0; mt < 2; mt++) {
            const int m = mt * 16 + q * 4;
            #pragma unroll
            for (int r = 0; r < 4; r++) {
                e2L[(m + r) * E2P + 2 * wv * 16 + r0]       = fmaxf(acc[mt][0][r] + bz0, 0.f);
                e2L[(m + r) * E2P + (2 * wv + 1) * 16 + r0] = fmaxf(acc[mt][1][r] + bz1, 0.f);
            }
        }
    }
    __syncthreads();

    // Per-graph edge sums (edge_graph sorted -> few runs per block)
    if (gidx[0] == gidx[EPB - 1]) {
        const int g = gidx[0];
        float s = 0.f;
        #pragma unroll
        for (int j = 0; j < EPB; j++) s += __bfloat162float(e1B[j * E1P + t]);
        atomicAdd(&ge1[(size_t)g * 256 + t], s);
        if (t < 128) {
            float s2 = 0.f;
            #pragma unroll
            for (int j = 0; j < EPB; j++) s2 += e2L[j * E2P + t];
            atomicAdd(&ge2[(size_t)g * 128 + t], s2);
        }
        if (t == 0) atomicAdd(&gecnt[g], (float)EPB);
    } else {
        int j = 0;
        while (j < EPB) {
            const int g = gidx[j];
            int j2 = j;
            float s = 0.f;
            while (j2 < EPB && gidx[j2] == g) { s += __bfloat162float(e1B[j2 * E1P + t]); j2++; }
            atomicAdd(&ge1[(size_t)g * 256 + t], s);
            if (t < 128) {
                float s2 = 0.f;
                for (int jj = j; jj < j2; jj++) s2 += e2L[jj * E2P + t];
                atomicAdd(&ge2[(size_t)g * 128 + t], s2);
            }
            if (t == 0) atomicAdd(&gecnt[g], (float)(j2 - j));
            j = j2;
        }
    }
}

// ---------------------------------------------------------------------------
// Aggregate kernel (v4): CHK=64 fat chunks (round-4-proven) + jog swizzle
// (S-read rows ks*32+q*8+i have jog key == q -> q-groups hit disjoint bank
// sets) + software-pipelined gather: eS/idL/segL double-buffered; next-chunk
// CSR ids load under e1, next-chunk ebf rows load (to regs) under e2;
// 3 barriers per chunk. Segment sums via indicator-MFMA in registers.
// LDS ~75 KB -> 2 blocks/CU (latency hidden by prefetch, not occupancy).
// ---------------------------------------------------------------------------
#define ANPB 16
#define CHK 64
#define ESP 40     // eS stride (32+8) bf16
#define E1CP 312   // 256 ch + jog(<=48) + 8 pad
#define E2CP 184   // 128 ch + jog(<=48) + 8 pad
#define JADDR(j, c, P) ((j) * (P) + (c) + ((((j) >> 3) & 3) << 4))

__global__ __launch_bounds__(256) void agg_kernel(
    const __hip_bfloat16* __restrict__ ebf,
    const int* __restrict__ roff, const int* __restrict__ soff,
    const int* __restrict__ csrR, const int* __restrict__ csrS,
    const __hip_bfloat16* __restrict__ We1t, const float* __restrict__ be1,
    const __hip_bfloat16* __restrict__ Wt2, const float* __restrict__ be2,
    __hip_bfloat16* __restrict__ i1d, __hip_bfloat16* __restrict__ o1d,
    __hip_bfloat16* __restrict__ i2d, __hip_bfloat16* __restrict__ o2d)
{
    __shared__ __hip_bfloat16 eS[2][CHK * ESP];     // 10 KB
    __shared__ __hip_bfloat16 e1C[CHK * E1CP];      // 39 KB
    __shared__ __hip_bfloat16 e2C[CHK * E2CP];      // 23 KB
    __shared__ int idL[2][CHK];
    __shared__ int segL[2][CHK];
    __shared__ int offL[ANPB + 1];

    const int t = threadIdx.x;
    int b = blockIdx.x;
    const int side = (b >= (N_NODES / ANPB));
    if (side) b -= N_NODES / ANPB;
    const int n0 = b * ANPB;
    const int* off = side ? soff : roff;
    const int* lst = side ? csrS : csrR;
    __hip_bfloat16* d1 = side ? o1d : i1d;
    __hip_bfloat16* d2 = side ? o2d : i2d;

    if (t <= ANPB) offL[t] = off[n0 + t];
    __syncthreads();
    const int base = offL[0], end = offL[ANPB];
    const int nchunks = (end - base + CHK - 1) / CHK;

    const int wv = t >> 6, ln = t & 63;
    const int r0 = ln & 15, q = ln >> 4;
    const int srow = t >> 2, scol = (t & 3) * 8;   // staging role: 256 thr = 64 rows x 4

    // register accumulators: S1 = Ind.e1 (16x256), S2 = Ind.e2 (16x128)
    f32x4 s1[4] = {{0.f,0.f,0.f,0.f},{0.f,0.f,0.f,0.f},
                   {0.f,0.f,0.f,0.f},{0.f,0.f,0.f,0.f}};
    f32x4 s2[2] = {{0.f,0.f,0.f,0.f},{0.f,0.f,0.f,0.f}};

    float bz1[4], bz2[2];
    #pragma unroll
    for (int nn = 0; nn < 4; nn++) bz1[nn] = be1[(wv * 4 + nn) * 16 + r0];
    #pragma unroll
    for (int nn = 0; nn < 2; nn++) bz2[nn] = be2[(wv * 2 + nn) * 16 + r0];

    // ---- prologue: chunk 0 ids/seg + data -> eS[0]
    if (t < CHK) {
        const int p = base + t;
        int sg = -1, id = 0;
        if (p < end) {
            id = lst[p];
            sg = 0;
            #pragma unroll
            for (int j = 1; j < ANPB; j++) sg += (p >= offL[j]) ? 1 : 0;
        }
        idL[0][t] = id; segL[0][t] = sg;
    }
    __syncthreads();
    {
        bf16x8 v = {0, 0, 0, 0, 0, 0, 0, 0};
        if (segL[0][srow] >= 0) v = *(const bf16x8*)&ebf[(size_t)idL[0][srow] * 32 + scol];
        *(bf16x8*)&eS[0][srow * ESP + scol] = v;
    }
    __syncthreads();   // barrier D0: eS[0] ready

    int cur = 0;
    for (int c = 0; c < nchunks; c++) {
        const int nxt = cur ^ 1;

        // issue next chunk ids (latency hides under e1)
        int idn = 0, sgn = -1;
        if (t < CHK) {
            const int p = base + (c + 1) * CHK + t;
            if (c + 1 < nchunks && p < end) {
                idn = lst[p];
                sgn = 0;
                #pragma unroll
                for (int j = 1; j < ANPB; j++) sgn += (p >= offL[j]) ? 1 : 0;
            }
        }

        // indicator fragments for this chunk (reused by S1 and S2)
        bf16x8 ind[2];
        #pragma unroll
        for (int ks = 0; ks < 2; ks++)
            #pragma unroll
            for (int i = 0; i < 8; i++)
                ind[ks][i] = (segL[cur][ks * 32 + q * 8 + i] == r0) ? (short)0x3F80 : (short)0;

        // e1 = relu(e @ We1 + be1): M=64 (4 mt), N=256, K=32
        #pragma unroll
        for (int mt = 0; mt < 4; mt++) {
            const bf16x8 a = *(const bf16x8*)&eS[cur][(mt * 16 + r0) * ESP + q * 8];
            #pragma unroll
            for (int nn = 0; nn < 4; nn++) {
                const int n = (wv * 4 + nn) * 16 + r0;
                const bf16x8 wb = *(const bf16x8*)&We1t[(size_t)n * 32 + q * 8];
                f32x4 cc = {0.f, 0.f, 0.f, 0.f};
                cc = __builtin_amdgcn_mfma_f32_16x16x32_bf16(a, wb, cc, 0, 0, 0);
                #pragma unroll
                for (int r = 0; r < 4; r++)
                    e1C[JADDR(mt * 16 + q * 4 + r, n, E1CP)] =
                        __float2bfloat16(fmaxf(cc[r] + bz1[nn], 0.f));
            }
        }
        if (t < CHK) { idL[nxt][t] = idn; segL[nxt][t] = sgn; }
        __syncthreads();   // barrier B: e1C + idL[nxt]/segL[nxt] ready

        // issue next chunk ebf loads into regs (hides under e2)
        bf16x8 pre = {0, 0, 0, 0, 0, 0, 0, 0};
        if (segL[nxt][srow] >= 0)
            pre = *(const bf16x8*)&ebf[(size_t)idL[nxt][srow] * 32 + scol];

        // S1 += Ind @ e1   (K=64 -> 2 ksteps)
        #pragma unroll
        for (int ks = 0; ks < 2; ks++) {
            #pragma unroll
            for (int nn = 0; nn < 4; nn++) {
                const int n = (wv * 4 + nn) * 16 + r0;
                bf16x8 bfr;
                #pragma unroll
                for (int i = 0; i < 8; i++)
                    bfr[i] = *(const short*)&e1C[JADDR(ks * 32 + q * 8 + i, n, E1CP)];
                s1[nn] = __builtin_amdgcn_mfma_f32_16x16x32_bf16(ind[ks], bfr, s1[nn], 0, 0, 0);
            }
        }

        // e2 = relu(e1 @ We2 + be2): M=64, N=128, K=256 (8 ksteps)
        #pragma unroll
        for (int mt = 0; mt < 4; mt++) {
            f32x4 cc[2] = {{0.f,0.f,0.f,0.f},{0.f,0.f,0.f,0.f}};
            #pragma unroll
            for (int ks = 0; ks < 8; ks++) {
                const bf16x8 a = *(const bf16x8*)&e1C[JADDR(mt * 16 + r0, ks * 32 + q * 8, E1CP)];
                #pragma unroll
                for (int nn = 0; nn < 2; nn++) {
                    const int n = (wv * 2 + nn) * 16 + r0;
                    const bf16x8 wb = *(const bf16x8*)&Wt2[(size_t)n * 256 + ks * 32 + q * 8];
                    cc[nn] = __builtin_amdgcn_mfma_f32_16x16x32_bf16(a, wb, cc[nn], 0, 0, 0);
                }
            }
            #pragma unroll
            for (int nn = 0; nn < 2; nn++) {
                const int n = (wv * 2 + nn) * 16 + r0;
                #pragma unroll
                for (int r = 0; r < 4; r++)
                    e2C[JADDR(mt * 16 + q * 4 + r, n, E2CP)] =
                        __float2bfloat16(fmaxf(cc[nn][r] + bz2[nn], 0.f));
            }
        }
        __syncthreads();   // barrier C: e2C ready

        // S2 += Ind @ e2
        #pragma unroll
        for (int ks = 0; ks < 2; ks++) {
            #pragma unroll
            for (int nn = 0; nn < 2; nn++) {
                const int n = (wv * 2 + nn) * 16 + r0;
                bf16x8 bfr;
                #pragma unroll
                for (int i = 0; i < 8; i++)
                    bfr[i] = *(const short*)&e2C[JADDR(ks * 32 + q * 8 + i, n, E2CP)];
                s2[nn] = __builtin_amdgcn_mfma_f32_16x16x32_bf16(ind[ks], bfr, s2[nn], 0, 0, 0);
            }
        }

        // stage next chunk from prefetched regs
        *(bf16x8*)&eS[nxt][srow * ESP + scol] = pre;
        __syncthreads();   // barrier D: eS[nxt] ready; e1C/e2C free
        cur = nxt;
    }

    // means: dump register sums (scaled) to LDS (plain layout), then
    // coalesced global store. Lane (r0,q) holds rows m=q*4+r, col n.
    {
        float inv[4];
        #pragma unroll
        for (int r = 0; r < 4; r++) {
            const int m = q * 4 + r;
            const int deg = offL[m + 1] - offL[m];
            inv[r] = 1.f / (float)(deg > 0 ? deg : 1);
        }
        #pragma unroll
        for (int nn = 0; nn < 4; nn++) {
            const int n = (wv * 4 + nn) * 16 + r0;
            #pragma unroll
            for (int r = 0; r < 4; r++)
                e1C[(q * 4 + r) * E1CP + n] = __float2bfloat16(s1[nn][r] * inv[r]);
        }
        #pragma unroll
        for (int nn = 0; nn < 2; nn++) {
            const int n = (wv * 2 + nn) * 16 + r0;
            #pragma unroll
            for (int r = 0; r < 4; r++)
                e2C[(q * 4 + r) * E2CP + n] = __float2bfloat16(s2[nn][r] * inv[r]);
        }
    }
    __syncthreads();
    for (int i = t; i < ANPB * 32; i += 256) {
        const int j = i >> 5, c8 = (i & 31) * 8;
        *(bf16x8*)&d1[(size_t)(n0 + j) * 256 + c8] = *(const bf16x8*)&e1C[j * E1CP + c8];
    }
    for (int i = t; i < ANPB * 16; i += 256) {
        const int j = i >> 4, c8 = (i & 15) * 8;
        *(bf16x8*)&d2[(size_t)(n0 + j) * 128 + c8] = *(const bf16x8*)&e2C[j * E2CP + c8];
    }
}

// ---------------------------------------------------------------------------
// Node kernel (dense): load dense bf16 mean matrices -> LDS; MFMA n1, n2;
// per-graph fp32 atomic sums.
// ---------------------------------------------------------------------------
#define NPB 16
#define XP  72
#define K1P 264
#define K2P 136

__global__ __launch_bounds__(256) void node_kernel_dense(
    const float* __restrict__ x,
    const int* __restrict__ node_graph,
    const __hip_bfloat16* __restrict__ i1d, const __hip_bfloat16* __restrict__ o1d,
    const __hip_bfloat16* __restrict__ i2d, const __hip_bfloat16* __restrict__ o2d,
    const __hip_bfloat16* __restrict__ Wn1t, const __hip_bfloat16* __restrict__ Win1t,
    const __hip_bfloat16* __restrict__ Wout1t, const float* __restrict__ bn1,
    const __hip_bfloat16* __restrict__ Wn2t, const __hip_bfloat16* __restrict__ Win2t,
    const __hip_bfloat16* __restrict__ Wout2t, const float* __restrict__ bn2,
    float* __restrict__ gn1, float* __restrict__ gn2, float* __restrict__ gncnt)
{
    __shared__ __hip_bfloat16 xB[NPB * XP];
    __shared__ __hip_bfloat16 i1B[NPB * K1P];
    __shared__ __hip_bfloat16 o1B[NPB * K1P];
    __shared__ __hip_bfloat16 i2B[NPB * K2P];
    __shared__ __hip_bfloat16 o2B[NPB * K2P];
    __shared__ __hip_bfloat16 n1B[NPB * K1P];
    __shared__ __hip_bfloat16 n2B[NPB * K2P];
    __shared__ int gI[NPB];

    const int t = threadIdx.x;
    const long n0 = (long)blockIdx.x * NPB;

    if (t < NPB) gI[t] = node_graph[n0 + t];
    for (int i = t; i < NPB * 16; i += 256) {
        const int j = i >> 4, c4 = (i & 15) * 4;
        const float4 v = *(const float4*)&x[(n0 + j) * 64 + c4];
        *(__hip_bfloat162*)&xB[j * XP + c4]     = __float22bfloat162_rn(make_float2(v.x, v.y));
        *(__hip_bfloat162*)&xB[j * XP + c4 + 2] = __float22bfloat162_rn(make_float2(v.z, v.w));
    }
    for (int i = t; i < NPB * 32; i += 256) {
        const int j = i >> 5, c8 = (i & 31) * 8;
        *(bf16x8*)&i1B[j * K1P + c8] = *(const bf16x8*)&i1d[(size_t)(n0 + j) * 256 + c8];
        *(bf16x8*)&o1B[j * K1P + c8] = *(const bf16x8*)&o1d[(size_t)(n0 + j) * 256 + c8];
    }
    for (int i = t; i < NPB * 16; i += 256) {
        const int j = i >> 4, c8 = (i & 15) * 8;
        *(bf16x8*)&i2B[j * K2P + c8] = *(const bf16x8*)&i2d[(size_t)(n0 + j) * 128 + c8];
        *(bf16x8*)&o2B[j * K2P + c8] = *(const bf16x8*)&o2d[(size_t)(n0 + j) * 128 + c8];
    }
    __syncthreads();

    const int wv = t >> 6, ln = t & 63;
    const int r0 = ln & 15, q = ln >> 4;

    // ---- n1 MFMA
    {
        f32x4 acc[4] = {{0.f,0.f,0.f,0.f},{0.f,0.f,0.f,0.f},
                        {0.f,0.f,0.f,0.f},{0.f,0.f,0.f,0.f}};
        #pragma unroll
        for (int ks = 0; ks < 2; ks++) {
            const int k0 = ks * 32 + q * 8;
            const bf16x8 a = *(const bf16x8*)&xB[r0 * XP + k0];
            #pragma unroll
            for (int nn = 0; nn < 4; nn++) {
                const int n = (wv * 4 + nn) * 16 + r0;
                const bf16x8 b = *(const bf16x8*)&Wn1t[(size_t)n * 64 + k0];
                acc[nn] = __builtin_amdgcn_mfma_f32_16x16x32_bf16(a, b, acc[nn], 0, 0, 0);
            }
        }
        #pragma unroll
        for (int ks = 0; ks < 8; ks++) {
            const int k0 = ks * 32 + q * 8;
            const bf16x8 a = *(const bf16x8*)&i1B[r0 * K1P + k0];
            #pragma unroll
            for (int nn = 0; nn < 4; nn++) {
                const int n = (wv * 4 + nn) * 16 + r0;
                const bf16x8 b = *(const bf16x8*)&Win1t[(size_t)n * 256 + k0];
                acc[nn] = __builtin_amdgcn_mfma_f32_16x16x32_bf16(a, b, acc[nn], 0, 0, 0);
            }
        }
        #pragma unroll
        for (int ks = 0; ks < 8; ks++) {
            const int k0 = ks * 32 + q * 8;
            const bf16x8 a = *(const bf16x8*)&o1B[r0 * K1P + k0];
            #pragma unroll
            for (int nn = 0; nn < 4; nn++) {
                const int n = (wv * 4 + nn) * 16 + r0;
                const bf16x8 b = *(const bf16x8*)&Wout1t[(size_t)n * 256 + k0];
                acc[nn] = __builtin_amdgcn_mfma_f32_16x16x32_bf16(a, b, acc[nn], 0, 0, 0);
            }
        }
        #pragma unroll
        for (int nn = 0; nn < 4; nn++) {
            const int n = (wv * 4 + nn) * 16 + r0;
            const float bz = bn1[n];
            #pragma unroll
            for (int r = 0; r < 4; r++) {
                const int m = q * 4 + r;
                n1B[m * K1P + n] = __float2bfloat16(fmaxf(acc[nn][r] + bz, 0.f));
            }
        }
    }
    __syncthreads();

    // ---- per-graph n1 sums
    if (gI[0] == gI[NPB - 1]) {
        float s = 0.f;
        #pragma unroll
        for (int j = 0; j < NPB; j++) s += __bfloat162float(n1B[j * K1P + t]);
        atomicAdd(&gn1[(size_t)gI[0] * 256 + t], s);
        if (t == 0) atomicAdd(&gncnt[gI[0]], (float)NPB);
    } else {
        int j = 0;
        while (j < NPB) {
            const int g = gI[j];
            int j2 = j;
            float s = 0.f;
            while (j2 < NPB && gI[j2] == g) { s += __bfloat162float(n1B[j2 * K1P + t]); j2++; }
            atomicAdd(&gn1[(size_t)g * 256 + t], s);
            if (t == 0) atomicAdd(&gncnt[g], (float)(j2 - j));
            j = j2;
        }
    }

    // ---- n2 MFMA
    {
        f32x4 acc[2] = {{0.f,0.f,0.f,0.f},{0.f,0.f,0.f,0.f}};
        #pragma unroll
        for (int ks = 0; ks < 8; ks++) {
            const int k0 = ks * 32 + q * 8;
            const bf16x8 a = *(const bf16x8*)&n1B[r0 * K1P + k0];
            #pragma unroll
            for (int nn = 0; nn < 2; nn++) {
                const int n = (wv * 2 + nn) * 16 + r0;
                const bf16x8 b = *(const bf16x8*)&Wn2t[(size_t)n * 256 + k0];
                acc[nn] = __builtin_amdgcn_mfma_f32_16x16x32_bf16(a, b, acc[nn], 0, 0, 0);
            }
        }
        #pragma unroll
        for (int ks = 0; ks < 4; ks++) {
            const int k0 = ks * 32 + q * 8;
            const bf16x8 a = *(const bf16x8*)&i2B[r0 * K2P + k0];
            #pragma unroll
            for (int nn = 0; nn < 2; nn++) {
                const int n = (wv * 2 + nn) * 16 + r0;
                const bf16x8 b = *(const bf16x8*)&Win2t[(size_t)n * 128 + k0];
                acc[nn] = __builtin_amdgcn_mfma_f32_16x16x32_bf16(a, b, acc[nn], 0, 0, 0);
            }
        }
        #pragma unroll
        for (int ks = 0; ks < 4; ks++) {
            const int k0 = ks * 32 + q * 8;
            const bf16x8 a = *(const bf16x8*)&o2B[r0 * K2P + k0];
            #pragma unroll
            for (int nn = 0; nn < 2; nn++) {
                const int n = (wv * 2 + nn) * 16 + r0;
                const bf16x8 b = *(const bf16x8*)&Wout2t[(size_t)n * 128 + k0];
                acc[nn] = __builtin_amdgcn_mfma_f32_16x16x32_bf16(a, b, acc[nn], 0, 0, 0);
            }
        }
        #pragma unroll
        for (int nn = 0; nn < 2; nn++) {
            const int n = (wv * 2 + nn) * 16 + r0;
            const float bz = bn2[n];
            #pragma unroll
            for (int r = 0; r < 4; r++) {
                const int m = q * 4 + r;
                n2B[m * K2P + n] = __float2bfloat16(fmaxf(acc[nn][r] + bz, 0.f));
            }
        }
    }
    __syncthreads();

    // ---- per-graph n2 sums
    if (t < 128) {
        if (gI[0] == gI[NPB - 1]) {
            float s = 0.f;
            #pragma unroll
            for (int j = 0; j < NPB; j++) s += __bfloat162float(n2B[j * K2P + t]);
            atomicAdd(&gn2[(size_t)gI[0] * 128 + t], s);
        } else {
            int j = 0;
            while (j < NPB) {
                const int g = gI[j];
                int j2 = j;
                float s = 0.f;
                while (j2 < NPB && gI[j2] == g) { s += __bfloat162float(n2B[j2 * K2P + t]); j2++; }
                atomicAdd(&gn2[(size_t)g * 128 + t], s);
                j = j2;
            }
        }
    }
}

// ---------------------------------------------------------------------------
// Graph kernel: one block per graph. u1, u2, state_value, action MLP, output.
// ---------------------------------------------------------------------------
__global__ __launch_bounds__(256) void graph_kernel(
    const float* __restrict__ u,
    const float* __restrict__ a,
    const float* __restrict__ ge1, const float* __restrict__ ge2,
    const float* __restrict__ gecnt,
    const float* __restrict__ gn1, const float* __restrict__ gn2,
    const float* __restrict__ gncnt,
    const float* __restrict__ Wg1, const float* __restrict__ Wgn1,
    const float* __restrict__ Wge1, const float* __restrict__ bg1,
    const float* __restrict__ Wg2, const float* __restrict__ Wgn2,
    const float* __restrict__ Wge2, const float* __restrict__ bg2,
    const float* __restrict__ Wga, const float* __restrict__ bga,
    const float* __restrict__ Wa1, const float* __restrict__ ba1,
    const float* __restrict__ Wa2, const float* __restrict__ ba2,
    const float* __restrict__ Wa3, const float* __restrict__ ba3,
    float* __restrict__ out)
{
    const int g = blockIdx.x;
    const int t = threadIdx.x;
    __shared__ float uL[64], mn1[256], me1[256], mn2[128], me2[128];
    __shared__ float u1L[256], u2L[128], hL[144], h1L[256], h2L[256];
    __shared__ float red[4];

    const float ec = 1.f / fmaxf(gecnt[g], 1.f);
    const float nc = 1.f / fmaxf(gncnt[g], 1.f);
    if (t < 64) uL[t] = u[(size_t)g * 64 + t];
    mn1[t] = gn1[(size_t)g * 256 + t] * nc;
    me1[t] = ge1[(size_t)g * 256 + t] * ec;
    if (t < 128) {
        mn2[t] = gn2[(size_t)g * 128 + t] * nc;
        me2[t] = ge2[(size_t)g * 128 + t] * ec;
    }
    if (t >= 136 && t < 144) hL[t] = 0.f;
    __syncthreads();

    {
        float acc = bg1[t];
        for (int k = 0; k < 64; k++)  acc = fmaf(uL[k],  Wg1[(size_t)k * 256 + t], acc);
        for (int k = 0; k < 256; k++) acc = fmaf(mn1[k], Wgn1[(size_t)k * 256 + t], acc);
        for (int k = 0; k < 256; k++) acc = fmaf(me1[k], Wge1[(size_t)k * 256 + t], acc);
        u1L[t] = fmaxf(acc, 0.f);
    }
    __syncthreads();
    if (t < 128) {
        float acc = bg2[t];
        for (int k = 0; k < 256; k++) acc = fmaf(u1L[k], Wg2[(size_t)k * 128 + t], acc);
        for (int k = 0; k < 128; k++) acc = fmaf(mn2[k], Wgn2[(size_t)k * 128 + t], acc);
        for (int k = 0; k < 128; k++) acc = fmaf(me2[k], Wge2[(size_t)k * 128 + t], acc);
        u2L[t] = fmaxf(acc, 0.f);
    }
    __syncthreads();
    if (t < 128) {
        float acc = bga[t];
        for (int k = 0; k < 128; k++) acc = fmaf(u2L[k], Wga[(size_t)k * 128 + t], acc);
        hL[t] = acc;
    }
    if (t >= 128 && t < 136) hL[t] = a[(size_t)g * 8 + (t - 128)];
    __syncthreads();
    {
        float acc = ba1[t];
        for (int k = 0; k < 136; k++) acc = fmaf(hL[k], Wa1[(size_t)k * 256 + t], acc);
        h1L[t] = fmaxf(acc, 0.f);
    }
    __syncthreads();
    {
        float acc = ba2[t];
        for (int k = 0; k < 256; k++) acc = fmaf(h1L[k], Wa2[(size_t)k * 256 + t], acc);
        h2L[t] = fmaxf(acc, 0.f);
    }
    __syncthreads();
    {
        float p = h2L[t] * Wa3[t];
        for (int off = 32; off > 0; off >>= 1) p += __shfl_down(p, off, 64);
        if ((t & 63) == 0) red[t >> 6] = p;
        __syncthreads();
        if (t == 0) out[g] = red[0] + red[1] + red[2] + red[3] + ba3[0];
    }
}

// ===========================================================================
// ==================   LEGACY ATOMIC-SCATTER PATH (fallback)  ===============
// ===========================================================================

__global__ __launch_bounds__(256) void edge_kernel(
    const float* __restrict__ e,
    const int* __restrict__ senders,
    const int* __restrict__ receivers,
    const int* __restrict__ edge_graph,
    const float* __restrict__ We1, const float* __restrict__ be1,
    const __hip_bfloat16* __restrict__ Wt2,
    const float* __restrict__ be2,
    unsigned long long* __restrict__ inc1u, unsigned long long* __restrict__ out1u,
    unsigned long long* __restrict__ inc2u, unsigned long long* __restrict__ out2u,
    float* __restrict__ rcnt, float* __restrict__ scnt,
    float* __restrict__ ge1, float* __restrict__ ge2, float* __restrict__ gecnt)
{
    __shared__ float eL[EPB * 32];
    __shared__ __hip_bfloat16 e1B[EPB * E1P];
    __shared__ float e2L[EPB * E2P];
    __shared__ int ridx[EPB], sidx[EPB], gidx[EPB];

    const int t = threadIdx.x;
    const long e0 = (long)blockIdx.x * EPB;

    for (int i = t; i < EPB * 32; i += 256) eL[i] = e[e0 * 32 + i];
    if (t < EPB) {
        ridx[t] = receivers[e0 + t];
        sidx[t] = senders[e0 + t];
        gidx[t] = edge_graph[e0 + t];
    }
    __syncthreads();

    {
        const int c0 = (t & 63) * 4;
        const int jb = (t >> 6) * 8;
        float4 acc[8];
        const float4 b4 = *(const float4*)&be1[c0];
        #pragma unroll
        for (int j = 0; j < 8; j++) acc[j] = b4;
        for (int k = 0; k < 32; k += 4) {
            float4 v[8];
            #pragma unroll
            for (int j = 0; j < 8; j++) v[j] = *(const float4*)&eL[(jb + j) * 32 + k];
            #pragma unroll
            for (int kk = 0; kk < 4; kk++) {
                const float4 w = *(const float4*)&We1[(size_t)(k + kk) * 256 + c0];
                #pragma unroll
                for (int j = 0; j < 8; j++) {
                    const float vv = ((const float*)&v[j])[kk];
                    acc[j].x = fmaf(vv, w.x, acc[j].x);
                    acc[j].y = fmaf(vv, w.y, acc[j].y);
                    acc[j].z = fmaf(vv, w.z, acc[j].z);
                    acc[j].w = fmaf(vv, w.w, acc[j].w);
                }
            }
        }
        #pragma unroll
        for (int j = 0; j < 8; j++) {
            const float2 p0 = make_float2(fmaxf(acc[j].x, 0.f), fmaxf(acc[j].y, 0.f));
            const float2 p1 = make_float2(fmaxf(acc[j].z, 0.f), fmaxf(acc[j].w, 0.f));
            *(__hip_bfloat162*)&e1B[(jb + j) * E1P + c0]     = __float22bfloat162_rn(p0);
            *(__hip_bfloat162*)&e1B[(jb + j) * E1P + c0 + 2] = __float22bfloat162_rn(p1);
        }
    }
    __syncthreads();

    {
        const int wv = t >> 6, ln = t & 63;
        const int r0 = ln & 15, q = ln >> 4;
        f32x4 acc[2][2] = {{{0.f,0.f,0.f,0.f},{0.f,0.f,0.f,0.f}},
                           {{0.f,0.f,0.f,0.f},{0.f,0.f,0.f,0.f}}};
        const int n0 = (2 * wv) * 16 + r0;
        const int n1 = (2 * wv + 1) * 16 + r0;
        #pragma unroll
        for (int kb = 0; kb < 8; kb++) {
            const int k0 = kb * 32 + q * 8;
            const bf16x8 a0 = *(const bf16x8*)&e1B[(r0) * E1P + k0];
            const bf16x8 a1 = *(const bf16x8*)&e1B[(16 + r0) * E1P + k0];
            const bf16x8 b0 = *(const bf16x8*)&Wt2[(size_t)n0 * 256 + k0];
            const bf16x8 b1 = *(const bf16x8*)&Wt2[(size_t)n1 * 256 + k0];
            acc[0][0] = __builtin_amdgcn_mfma_f32_16x16x32_bf16(a0, b0, acc[0][0], 0, 0, 0);
            acc[0][1] = __builtin_amdgcn_mfma_f32_16x16x32_bf16(a0, b1, acc[0][1], 0, 0, 0);
            acc[1][0] = __builtin_amdgcn_mfma_f32_16x16x32_bf16(a1, b0, acc[1][0], 0, 0, 0);
            acc[1][1] = __builtin_amdgcn_mfma_f32_16x16x32_bf16(a1, b1, acc[1][1], 0, 0, 0);
        }
        const float bz0 = be2[2 * wv * 16 + r0];
        const float bz1 = be2[(2 * wv + 1) * 16 + r0];
        #pragma unroll
        for (int mt = 0; mt < 2; mt++) {
            const int m = mt * 16 + q * 4;
            #pragma unroll
            for (int r = 0; r < 4; r++) {
                e2L[(m + r) * E2P + 2 * wv * 16 + r0]       = fmaxf(acc[mt][0][r] + bz0, 0.f);
                e2L[(m + r) * E2P + (2 * wv + 1) * 16 + r0] = fmaxf(acc[mt][1][r] + bz1, 0.f);
            }
        }
    }
    __syncthreads();

    {
        const int w = t & 63;
        const int ep = (t >> 6) & 1;
        unsigned long long* arr = (t < 128) ? inc1u : out1u;
        const int* idx = (t < 128) ? ridx : sidx;
        #pragma unroll
        for (int jj = 0; jj < EPB / 2; jj++) {
            const int j = jj * 2 + ep;
            const float2 v0 = __bfloat1622float2(*(const __hip_bfloat162*)&e1B[j * E1P + 4 * w]);
            const float2 v1 = __bfloat1622float2(*(const __hip_bfloat162*)&e1B[j * E1P + 4 * w + 2]);
            float4 v; v.x = v0.x; v.y = v0.y; v.z = v1.x; v.w = v1.y;
            atomicAdd(&arr[(size_t)idx[j] * 64 + w], pk16x4(v));
        }
    }
    {
        const int w = t & 31;
        const int eq = (t >> 5) & 3;
        unsigned long long* arr = (t < 128) ? inc2u : out2u;
        const int* idx = (t < 128) ? ridx : sidx;
        #pragma unroll
        for (int jj = 0; jj < EPB / 4; jj++) {
            const int j = jj * 4 + eq;
            const float4 v = *(const float4*)&e2L[j * E2P + 4 * w];
            atomicAdd(&arr[(size_t)idx[j] * 32 + w], pk16x4(v));
        }
    }
    if (gidx[0] == gidx[EPB - 1]) {
        const int g = gidx[0];
        float s = 0.f;
        #pragma unroll
        for (int j = 0; j < EPB; j++) s += __bfloat162float(e1B[j * E1P + t]);
        atomicAdd(&ge1[(size_t)g * 256 + t], s);
        if (t < 128) {
            float s2 = 0.f;
            #pragma unroll
            for (int j = 0; j < EPB; j++) s2 += e2L[j * E2P + t];
            atomicAdd(&ge2[(size_t)g * 128 + t], s2);
        }
        if (t == 0) atomicAdd(&gecnt[g], (float)EPB);
    } else {
        int j = 0;
        while (j < EPB) {
            const int g = gidx[j];
            int j2 = j;
            float s = 0.f;
            while (j2 < EPB && gidx[j2] == g) { s += __bfloat162float(e1B[j2 * E1P + t]); j2++; }
            atomicAdd(&ge1[(size_t)g * 256 + t], s);
            if (t < 128) {
                float s2 = 0.f;
                for (int jj = j; jj < j2; jj++) s2 += e2L[jj * E2P + t];
                atomicAdd(&ge2[(size_t)g * 128 + t], s2);
            }
            if (t == 0) atomicAdd(&gecnt[g], (float)(j2 - j));
            j = j2;
        }
    }
    if (t < EPB) {
        atomicAdd(&rcnt[ridx[t]], 1.f);
        atomicAdd(&scnt[sidx[t]], 1.f);
    }
}

__global__ __launch_bounds__(256) void node_kernel(
    const float* __restrict__ x,
    const int* __restrict__ node_graph,
    const unsigned long long* __restrict__ inc1u, const unsigned long long* __restrict__ out1u,
    const unsigned long long* __restrict__ inc2u, const unsigned long long* __restrict__ out2u,
    const float* __restrict__ rcnt, const float* __restrict__ scnt,
    const __hip_bfloat16* __restrict__ Wn1t, const __hip_bfloat16* __restrict__ Win1t,
    const __hip_bfloat16* __restrict__ Wout1t, const float* __restrict__ bn1,
    const __hip_bfloat16* __restrict__ Wn2t, const __hip_bfloat16* __restrict__ Win2t,
    const __hip_bfloat16* __restrict__ Wout2t, const float* __restrict__ bn2,
    float* __restrict__ gn1, float* __restrict__ gn2, float* __restrict__ gncnt)
{
    __shared__ __hip_bfloat16 xB[NPB * XP];
    __shared__ __hip_bfloat16 i1B[NPB * K1P];
    __shared__ __hip_bfloat16 o1B[NPB * K1P];
    __shared__ __hip_bfloat16 i2B[NPB * K2P];
    __shared__ __hip_bfloat16 o2B[NPB * K2P];
    __shared__ __hip_bfloat16 n1B[NPB * K1P];
    __shared__ __hip_bfloat16 n2B[NPB * K2P];
    __shared__ int gI[NPB];
    __shared__ float rrcp[NPB], srcp[NPB];

    const int t = threadIdx.x;
    const long n0 = (long)blockIdx.x * NPB;

    if (t < NPB) {
        gI[t] = node_graph[n0 + t];
        rrcp[t] = FXI16 / fmaxf(rcnt[n0 + t], 1.f);
        srcp[t] = FXI16 / fmaxf(scnt[n0 + t], 1.f);
    }
    for (int i = t; i < NPB * 16; i += 256) {
        const int j = i >> 4, c4 = (i & 15) * 4;
        const float4 v = *(const float4*)&x[(n0 + j) * 64 + c4];
        *(__hip_bfloat162*)&xB[j * XP + c4]     = __float22bfloat162_rn(make_float2(v.x, v.y));
        *(__hip_bfloat162*)&xB[j * XP + c4 + 2] = __float22bfloat162_rn(make_float2(v.z, v.w));
    }
    __syncthreads();

    for (int i = t; i < NPB * 64; i += 256) {
        const int j = i >> 6, w = i & 63;
        const size_t n = (size_t)(n0 + j);
        const unsigned long long av = inc1u[n * 64 + w];
        const unsigned long long bv = out1u[n * 64 + w];
        const float rr = rrcp[j], sr = srcp[j];
        const float2 a01 = make_float2((float)(unsigned int)(av & 0xFFFF) * rr,
                                       (float)(unsigned int)((av >> 16) & 0xFFFF) * rr);
        const float2 a23 = make_float2((float)(unsigned int)((av >> 32) & 0xFFFF) * rr,
                                       (float)(unsigned int)(av >> 48) * rr);
        const float2 b01 = make_float2((float)(unsigned int)(bv & 0xFFFF) * sr,
                                       (float)(unsigned int)((bv >> 16) & 0xFFFF) * sr);
        const float2 b23 = make_float2((float)(unsigned int)((bv >> 32) & 0xFFFF) * sr,
                                       (float)(unsigned int)(bv >> 48) * sr);
        *(__hip_bfloat162*)&i1B[j * K1P + 4 * w]     = __float22bfloat162_rn(a01);
        *(__hip_bfloat162*)&i1B[j * K1P + 4 * w + 2] = __float22bfloat162_rn(a23);
        *(__hip_bfloat162*)&o1B[j * K1P + 4 * w]     = __float22bfloat162_rn(b01);
        *(__hip_bfloat162*)&o1B[j * K1P + 4 * w + 2] = __float22bfloat162_rn(b23);
    }
    for (int i = t; i < NPB * 32; i += 256) {
        const int j = i >> 5, w = i & 31;
        const size_t n = (size_t)(n0 + j);
        const unsigned long long av = inc2u[n * 32 + w];
        const unsigned long long bv = out2u[n * 32 + w];
        const float rr = rrcp[j], sr = srcp[j];
        const float2 a01 = make_float2((float)(unsigned int)(av & 0xFFFF) * rr,
                                       (float)(unsigned int)((av >> 16) & 0xFFFF) * rr);
        const float2 a23 = make_float2((float)(unsigned int)((av >> 32) & 0xFFFF) * rr,
                                       (float)(unsigned int)(av >> 48) * rr);
        const float2 b01 = make_float2((float)(unsigned int)(bv & 0xFFFF) * sr,
                                       (float)(unsigned int)((bv >> 16) & 0xFFFF) * sr);
        const float2 b23 = make_float2((float)(unsigned int)((bv >> 32) & 0xFFFF) * sr,
                                       (float)(unsigned int)(bv >> 48) * sr);
        *(__hip_bfloat162*)&i2B[j * K2P + 4 * w]     = __float22bfloat162_rn(a01);
        *(__hip_bfloat162*)&i2B[j * K2P + 4 * w + 2] = __float22bfloat162_rn(a23);
        *(__hip_bfloat162*)&o2B[j * K2P + 4 * w]     = __float22bfloat162_rn(b01);
        *(__hip_bfloat162*)&o2B[j * K2P + 4 * w + 2] = __float22bfloat162_rn(b23);
    }
    __syncthreads();

    const int wv = t >> 6, ln = t & 63;
    const int r0 = ln & 15, q = ln >> 4;

    {
        f32x4 acc[4] = {{0.f,0.f,0.f,0.f},{0.f,0.f,0.f,0.f},
                        {0.f,0.f,0.f,0.f},{0.f,0.f,0.f,0.f}};
        #pragma unroll
        for (int ks = 0; ks < 2; ks++) {
            const int k0 = ks * 32 + q * 8;
            const bf16x8 a = *(const bf16x8*)&xB[r0 * XP + k0];
            #pragma unroll
            for (int nn = 0; nn < 4; nn++) {
                const int n = (wv * 4 + nn) * 16 + r0;
                const bf16x8 b = *(const bf16x8*)&Wn1t[(size_t)n * 64 + k0];
                acc[nn] = __builtin_amdgcn_mfma_f32_16x16x32_bf16(a, b, acc[nn], 0, 0, 0);
            }
        }
        #pragma unroll
        for (int ks = 0; ks < 8; ks++) {
            const int k0 = ks * 32 + q * 8;
            const bf16x8 a = *(const bf16x8*)&i1B[r0 * K1P + k0];
            #pragma unroll
            for (int nn = 0; nn < 4; nn++) {
                const int n = (wv * 4 + nn) * 16 + r0;
                const bf16x8 b = *(const bf16x8*)&Win1t[(size_t)n * 256 + k0];
                acc[nn] = __builtin_amdgcn_mfma_f32_16x16x32_bf16(a, b, acc[nn], 0, 0, 0);
            }
        }
        #pragma unroll
        for (int ks = 0; ks < 8; ks++) {
            const int k0 = ks * 32 + q * 8;
            const bf16x8 a = *(const bf16x8*)&o1B[r0 * K1P + k0];
            #pragma unroll
            for (int nn = 0; nn < 4; nn++) {
                const int n = (wv * 4 + nn) * 16 + r0;
                const bf16x8 b = *(const bf16x8*)&Wout1t[(size_t)n * 256 + k0];
                acc[nn] = __builtin_amdgcn_mfma_f32_16x16x32_bf16(a, b, acc[nn], 0, 0, 0);
            }
        }
        #pragma unroll
        for (int nn = 0; nn < 4; nn++) {
            const int n = (wv * 4 + nn) * 16 + r0;
            const float bz = bn1[n];
            #pragma unroll
            for (int r = 0; r < 4; r++) {
                const int m = q * 4 + r;
                n1B[m * K1P + n] = __float2bfloat16(fmaxf(acc[nn][r] + bz, 0.f));
            }
        }
    }
    __syncthreads();

    if (gI[0] == gI[NPB - 1]) {
        float s = 0.f;
        #pragma unroll
        for (int j = 0; j < NPB; j++) s += __bfloat162float(n1B[j * K1P + t]);
        atomicAdd(&gn1[(size_t)gI[0] * 256 + t], s);
        if (t == 0) atomicAdd(&gncnt[gI[0]], (float)NPB);
    } else {
        int j = 0;
        while (j < NPB) {
            const int g = gI[j];
            int j2 = j;
            float s = 0.f;
            while (j2 < NPB && gI[j2] == g) { s += __bfloat162float(n1B[j2 * K1P + t]); j2++; }
            atomicAdd(&gn1[(size_t)g * 256 + t], s);
            if (t == 0) atomicAdd(&gncnt[g], (float)(j2 - j));
            j = j2;
        }
    }

    {
        f32x4 acc[2] = {{0.f,0.f,0.f,0.f},{0.f,0.f,0.f,0.f}};
        #pragma unroll
        for (int ks = 0; ks < 8; ks++) {
            const int k0 = ks * 32 + q * 8;
            const bf16x8 a = *(const bf16x8*)&n1B[r0 * K1P + k0];
            #pragma unroll
            for (int nn = 0; nn < 2; nn++) {
                const int n = (wv * 2 + nn) * 16 + r0;
                const bf16x8 b = *(const bf16x8*)&Wn2t[(size_t)n * 256 + k0];
                acc[nn] = __builtin_amdgcn_mfma_f32_16x16x32_bf16(a, b, acc[nn], 0, 0, 0);
            }
        }
        #pragma unroll
        for (int ks = 0; ks < 4; ks++) {
            const int k0 = ks * 32 + q * 8;
            const bf16x8 a = *(const bf16x8*)&i2B[r0 * K2P + k0];
            #pragma unroll
            for (int nn = 0; nn < 2; nn++) {
                const int n = (wv * 2 + nn) * 16 + r0;
                const bf16x8 b = *(const bf16x8*)&Win2t[(size_t)n * 128 + k0];
                acc[nn] = __builtin_amdgcn_mfma_f32_16x16x32_bf16(a, b, acc[nn], 0, 0, 0);
            }
        }
        #pragma unroll
        for (int ks = 0; ks < 4; ks++) {
            const int k0 = ks * 32 + q * 8;
            const bf16x8 a = *(const bf16x8*)&o2B[r0 * K2P + k0];
            #pragma unroll
            for (int nn = 0; nn < 2; nn++) {
                const int n = (wv * 2 + nn) * 16 + r0;
                const bf16x8 b = *(const bf16x8*)&Wout2t[(size_t)n * 128 + k0];
                acc[nn] = __builtin_amdgcn_mfma_f32_16x16x32_bf16(a, b, acc[nn], 0, 0, 0);
            }
        }
        #pragma unroll
        for (int nn = 0; nn < 2; nn++) {
            const int n = (wv * 2 + nn) * 16 + r0;
            const float bz = bn2[n];
            #pragma unroll
            for (int r = 0; r < 4; r++) {
                const int m = q * 4 + r;
                n2B[m * K2P + n] = __float2bfloat16(fmaxf(acc[nn][r] + bz, 0.f));
            }
        }
    }
    __syncthreads();

    if (t < 128) {
        if (gI[0] == gI[NPB - 1]) {
            float s = 0.f;
            #pragma unroll
            for (int j = 0; j < NPB; j++) s += __bfloat162float(n2B[j * K2P + t]);
            atomicAdd(&gn2[(size_t)gI[0] * 128 + t], s);
        } else {
            int j = 0;
            while (j < NPB) {
                const int g = gI[j];
                int j2 = j;
                float s = 0.f;
                while (j2 < NPB && gI[j2] == g) { s += __bfloat162float(n2B[j2 * K2P + t]); j2++; }
                atomicAdd(&gn2[(size_t)g * 128 + t], s);
                j = j2;
            }
        }
    }
}

// ---------------------------------------------------------------------------
extern "C" void kernel_launch(void* const* d_in, const int* in_sizes, int n_in,
                              void* d_out, int out_size, void* d_ws, size_t ws_size,
                              hipStream_t stream) {
    const float* x          = (const float*)d_in[0];
    const float* e          = (const float*)d_in[1];
    const float* u          = (const float*)d_in[2];
    const float* a          = (const float*)d_in[3];
    const int*   senders    = (const int*)d_in[4];
    const int*   receivers  = (const int*)d_in[5];
    const int*   node_graph = (const int*)d_in[6];
    const int*   edge_graph = (const int*)d_in[7];
    const float* We1 = (const float*)d_in[8];  const float* be1 = (const float*)d_in[9];
    const float* Wn1 = (const float*)d_in[10]; const float* Win1 = (const float*)d_in[11];
    const float* Wout1 = (const float*)d_in[12]; const float* bn1 = (const float*)d_in[13];
    const float* Wg1 = (const float*)d_in[14]; const float* Wgn1 = (const float*)d_in[15];
    const float* Wge1 = (const float*)d_in[16]; const float* bg1 = (const float*)d_in[17];
    const float* We2 = (const float*)d_in[18]; const float* be2 = (const float*)d_in[19];
    const float* Wn2 = (const float*)d_in[20]; const float* Win2 = (const float*)d_in[21];
    const float* Wout2 = (const float*)d_in[22]; const float* bn2 = (const float*)d_in[23];
    const float* Wg2 = (const float*)d_in[24]; const float* Wgn2 = (const float*)d_in[25];
    const float* Wge2 = (const float*)d_in[26]; const float* bg2 = (const float*)d_in[27];
    const float* Wga = (const float*)d_in[28]; const float* bga = (const float*)d_in[29];
    const float* Wa1 = (const float*)d_in[30]; const float* ba1 = (const float*)d_in[31];
    const float* Wa2 = (const float*)d_in[32]; const float* ba2 = (const float*)d_in[33];
    const float* Wa3 = (const float*)d_in[34]; const float* ba3 = (const float*)d_in[35];

    // ---------------- recompute-aggregate CSR path (~116 MB) ----------------
    {
        char* p = (char*)d_ws;
        auto take = [&p](size_t bytes) {
            char* q = p; p += (bytes + 15) & ~(size_t)15; return q;
        };
        // zeroed region (single small memset)
        unsigned int* rcntU = (unsigned int*)take((size_t)N_NODES * 4);
        unsigned int* scntU = (unsigned int*)take((size_t)N_NODES * 4);
        float* ge1   = (float*)take((size_t)N_GRAPHS * 256 * 4);
        float* ge2   = (float*)take((size_t)N_GRAPHS * 128 * 4);
        float* gecnt = (float*)take((size_t)N_GRAPHS * 4);
        float* gn1   = (float*)take((size_t)N_GRAPHS * 256 * 4);
        float* gn2   = (float*)take((size_t)N_GRAPHS * 128 * 4);
        float* gncnt = (float*)take((size_t)N_GRAPHS * 4);
        const size_t zero_bytes = (size_t)(p - (char*)d_ws);
        // fully-overwritten region
        int* roff = (int*)take((size_t)(N_NODES + 1) * 4);
        int* soff = (int*)take((size_t)(N_NODES + 1) * 4);
        unsigned int* wpR = (unsigned int*)take((size_t)N_NODES * 4);
        unsigned int* wpS = (unsigned int*)take((size_t)N_NODES * 4);
        unsigned int* tsR = (unsigned int*)take(256 * 4);
        unsigned int* tsS = (unsigned int*)take(256 * 4);
        int* csrR = (int*)take((size_t)N_EDGES * 4);
        int* csrS = (int*)take((size_t)N_EDGES * 4);
        __hip_bfloat16* ebf = (__hip_bfloat16*)take((size_t)N_EDGES * 32 * 2);
        // dense bf16 mean matrices
        __hip_bfloat16* i1d = (__hip_bfloat16*)take((size_t)N_NODES * 256 * 2);
        __hip_bfloat16* o1d = (__hip_bfloat16*)take((size_t)N_NODES * 256 * 2);
        __hip_bfloat16* i2d = (__hip_bfloat16*)take((size_t)N_NODES * 128 * 2);
        __hip_bfloat16* o2d = (__hip_bfloat16*)take((size_t)N_NODES * 128 * 2);
        // bf16 transposed weights
        __hip_bfloat16* Wt2    = (__hip_bfloat16*)take((size_t)128 * 256 * 2);
        __hip_bfloat16* Wn1t   = (__hip_bfloat16*)take((size_t)256 * 64 * 2);
        __hip_bfloat16* Win1t  = (__hip_bfloat16*)take((size_t)256 * 256 * 2);
        __hip_bfloat16* Wout1t = (__hip_bfloat16*)take((size_t)256 * 256 * 2);
        __hip_bfloat16* Wn2t   = (__hip_bfloat16*)take((size_t)128 * 256 * 2);
        __hip_bfloat16* Win2t  = (__hip_bfloat16*)take((size_t)128 * 128 * 2);
        __hip_bfloat16* Wout2t = (__hip_bfloat16*)take((size_t)128 * 128 * 2);
        __hip_bfloat16* We1t   = (__hip_bfloat16*)take((size_t)256 * 32 * 2);
        const size_t needed = (size_t)(p - (char*)d_ws);

        if (ws_size >= needed) {
            hipMemsetAsync(d_ws, 0, zero_bytes, stream);

            prep_kernel<<<992, 256, 0, stream>>>(
                We2, Wn1, Win1, Wout1, Wn2, Win2, Wout2, We1,
                Wt2, Wn1t, Win1t, Wout1t, Wn2t, Win2t, Wout2t, We1t);

            convert_e_kernel<<<(N_EDGES * 32 / 8 + 255) / 256, 256, 0, stream>>>(e, ebf);

            count_kernel<<<(N_EDGES + 255) / 256, 256, 0, stream>>>(
                senders, receivers, rcntU, scntU);
            scan_tile_sum<<<2 * NTILES, 256, 0, stream>>>(rcntU, scntU, tsR, tsS);
            scan_tile_offsets<<<1, 256, 0, stream>>>(tsR, tsS, roff, soff);
            scan_finalize<<<2 * NTILES, 256, 0, stream>>>(
                rcntU, scntU, tsR, tsS, roff, soff, wpR, wpS);
            csr_fill<<<(N_EDGES + 255) / 256, 256, 0, stream>>>(
                senders, receivers, wpR, wpS, csrR, csrS);

            edge_kernel_e2<<<N_EDGES / EPB, 256, 0, stream>>>(
                e, edge_graph, We1t, be1, Wt2, be2, ge1, ge2, gecnt);

            agg_kernel<<<2 * (N_NODES / ANPB), 256, 0, stream>>>(
                ebf, roff, soff, csrR, csrS, We1t, be1, Wt2, be2,
                i1d, o1d, i2d, o2d);

            node_kernel_dense<<<N_NODES / NPB, 256, 0, stream>>>(
                x, node_graph, i1d, o1d, i2d, o2d,
                Wn1t, Win1t, Wout1t, bn1, Wn2t, Win2t, Wout2t, bn2,
                gn1, gn2, gncnt);

            graph_kernel<<<N_GRAPHS, 256, 0, stream>>>(
                u, a, ge1, ge2, gecnt, gn1, gn2, gncnt,
                Wg1, Wgn1, Wge1, bg1, Wg2, Wgn2, Wge2, bg2,
                Wga, bga, Wa1, ba1, Wa2, ba2, Wa3, ba3, (float*)d_out);
            return;
        }
    }

    // ---------------- legacy atomic-scatter path (fallback) ----------------
    unsigned long long* uw = (unsigned long long*)d_ws;
    unsigned long long* inc1u = uw;                       uw += (size_t)N_NODES * 64;
    unsigned long long* out1u = uw;                       uw += (size_t)N_NODES * 64;
    unsigned long long* inc2u = uw;                       uw += (size_t)N_NODES * 32;
    unsigned long long* out2u = uw;                       uw += (size_t)N_NODES * 32;
    float* fw = (float*)uw;
    float* rcnt = fw;  fw += N_NODES;
    float* scnt = fw;  fw += N_NODES;
    float* ge1  = fw;  fw += (size_t)N_GRAPHS * 256;
    float* ge2  = fw;  fw += (size_t)N_GRAPHS * 128;
    float* gecnt = fw; fw += N_GRAPHS;
    float* gn1  = fw;  fw += (size_t)N_GRAPHS * 256;
    float* gn2  = fw;  fw += (size_t)N_GRAPHS * 128;
    float* gncnt = fw; fw += N_GRAPHS;
    const size_t total_bytes = (char*)fw - (char*)d_ws;
    __hip_bfloat16* bw = (__hip_bfloat16*)fw;
    __hip_bfloat16* Wt2    = bw;  bw += 128 * 256;
    __hip_bfloat16* Wn1t   = bw;  bw += 256 * 64;
    __hip_bfloat16* Win1t  = bw;  bw += 256 * 256;
    __hip_bfloat16* Wout1t = bw;  bw += 256 * 256;
    __hip_bfloat16* Wn2t   = bw;  bw += 128 * 256;
    __hip_bfloat16* Win2t  = bw;  bw += 128 * 128;
    __hip_bfloat16* Wout2t = bw;  bw += 128 * 128;
    __hip_bfloat16* We1t   = bw;  bw += 256 * 32;

    hipMemsetAsync(d_ws, 0, total_bytes, stream);

    prep_kernel<<<992, 256, 0, stream>>>(
        We2, Wn1, Win1, Wout1, Wn2, Win2, Wout2, We1,
        Wt2, Wn1t, Win1t, Wout1t, Wn2t, Win2t, Wout2t, We1t);

    edge_kernel<<<N_EDGES / EPB, 256, 0, stream>>>(
        e, senders, receivers, edge_graph, We1, be1, Wt2, be2,
        inc1u, out1u, inc2u, out2u, rcnt, scnt, ge1, ge2, gecnt);

    node_kernel<<<N_NODES / NPB, 256, 0, stream>>>(
        x, node_graph, inc1u, out1u, inc2u, out2u, rcnt, scnt,
        Wn1t, Win1t, Wout1t, bn1, Wn2t, Win2t, Wout2t, bn2, gn1, gn2, gncnt);

    graph_kernel<<<N_GRAPHS, 256, 0, stream>>>(
        u, a, ge1, ge2, gecnt, gn1, gn2, gncnt,
        Wg1, Wgn1, Wge1, bg1, Wg2, Wgn2, Wge2, bg2,
        Wga, bga, Wa1, ba1, Wa2, ba2, Wa3, ba3, (float*)d_out);
}